// Round 1
// baseline (1175.763 us; speedup 1.0000x reference)
//
#include <hip/hip_runtime.h>
#include <hip/hip_bf16.h>
#include <cstddef>

#define BS 8
#define NQ 900
#define DM 256
#define LEN_V 13294

// ---------------------------------------------------------------------------
// Generic tiled fp32 GEMM: C[M,N] = (A [+ A2]) @ B[K,N] + bias, optional relu
// 64x64 tile, BK=16, 256 threads, 4x4 per thread.
// ---------------------------------------------------------------------------
__global__ __launch_bounds__(256) void gemm_kernel(
    const float* __restrict__ A, const float* __restrict__ A2,
    const float* __restrict__ B, const float* __restrict__ bias,
    float* __restrict__ C, int M, int N, int K, int relu)
{
    __shared__ float As[16][68];
    __shared__ float Bs[16][68];
    const int tid = threadIdx.x;
    const int row0 = blockIdx.x * 64;
    const int col0 = blockIdx.y * 64;
    const int ty = tid >> 4;        // 0..15
    const int tx = tid & 15;        // 0..15
    const int arow = tid >> 2;      // 0..63
    const int acol = (tid & 3) * 4; // 0,4,8,12
    const int brow = tid >> 4;      // 0..15
    const int bcol = (tid & 15) * 4;

    float acc[4][4] = {};

    for (int k0 = 0; k0 < K; k0 += 16) {
        // A tile (64 rows x 16 k), transposed into As[k][m]
        {
            int r = row0 + arow;
            float4 a = make_float4(0.f, 0.f, 0.f, 0.f);
            if (r < M) {
                a = *(const float4*)(A + (size_t)r * K + k0 + acol);
                if (A2) {
                    float4 a2 = *(const float4*)(A2 + (size_t)r * K + k0 + acol);
                    a.x += a2.x; a.y += a2.y; a.z += a2.z; a.w += a2.w;
                }
            }
            As[acol + 0][arow] = a.x;
            As[acol + 1][arow] = a.y;
            As[acol + 2][arow] = a.z;
            As[acol + 3][arow] = a.w;
        }
        // B tile (16 k x 64 cols)
        {
            float4 b = *(const float4*)(B + (size_t)(k0 + brow) * N + col0 + bcol);
            *(float4*)&Bs[brow][bcol] = b;
        }
        __syncthreads();
        #pragma unroll
        for (int kk = 0; kk < 16; ++kk) {
            float a[4], b[4];
            #pragma unroll
            for (int i = 0; i < 4; ++i) a[i] = As[kk][ty * 4 + i];
            #pragma unroll
            for (int j = 0; j < 4; ++j) b[j] = Bs[kk][tx * 4 + j];
            #pragma unroll
            for (int i = 0; i < 4; ++i)
                #pragma unroll
                for (int j = 0; j < 4; ++j)
                    acc[i][j] += a[i] * b[j];
        }
        __syncthreads();
    }

    const float4 bv = *(const float4*)(bias + col0 + tx * 4);
    #pragma unroll
    for (int i = 0; i < 4; ++i) {
        int r = row0 + ty * 4 + i;
        if (r >= M) continue;
        float4 o;
        o.x = acc[i][0] + bv.x;
        o.y = acc[i][1] + bv.y;
        o.z = acc[i][2] + bv.z;
        o.w = acc[i][3] + bv.w;
        if (relu) {
            o.x = fmaxf(o.x, 0.f); o.y = fmaxf(o.y, 0.f);
            o.z = fmaxf(o.z, 0.f); o.w = fmaxf(o.w, 0.f);
        }
        *(float4*)(C + (size_t)r * N + col0 + tx * 4) = o;
    }
}

// ---------------------------------------------------------------------------
// Self-attention: one thread per (b,h,q), streaming online softmax over keys.
// q,k,v layouts: (BS, NQ, 256) with head h at [h*32, h*32+32).
// ---------------------------------------------------------------------------
__global__ __launch_bounds__(256) void attn_kernel(
    const float* __restrict__ q, const float* __restrict__ k,
    const float* __restrict__ v, float* __restrict__ out)
{
    int t = blockIdx.x * 256 + threadIdx.x;   // ((b*8+h)*900 + qi)
    if (t >= BS * 8 * NQ) return;
    int qi = t % NQ;
    int bh = t / NQ;
    int h = bh & 7, b = bh >> 3;
    const float scale = 0.17677669529663687f; // 1/sqrt(32)

    float qv[32];
    {
        const float* qp = q + ((size_t)(b * NQ + qi) * DM + h * 32);
        #pragma unroll
        for (int i = 0; i < 8; ++i) {
            float4 f = *(const float4*)(qp + i * 4);
            qv[4 * i + 0] = f.x * scale; qv[4 * i + 1] = f.y * scale;
            qv[4 * i + 2] = f.z * scale; qv[4 * i + 3] = f.w * scale;
        }
    }
    float m = -3.0e38f, l = 0.f;
    float oacc[32];
    #pragma unroll
    for (int d = 0; d < 32; ++d) oacc[d] = 0.f;

    const float* kbase = k + ((size_t)b * NQ) * DM + h * 32;
    const float* vbase = v + ((size_t)b * NQ) * DM + h * 32;
    for (int j = 0; j < NQ; ++j) {
        const float* kp = kbase + (size_t)j * DM;
        float s = 0.f;
        #pragma unroll
        for (int i = 0; i < 8; ++i) {
            float4 f = *(const float4*)(kp + i * 4);
            s += qv[4 * i + 0] * f.x + qv[4 * i + 1] * f.y
               + qv[4 * i + 2] * f.z + qv[4 * i + 3] * f.w;
        }
        if (s > m) {
            float corr = __expf(m - s);
            l *= corr;
            #pragma unroll
            for (int d = 0; d < 32; ++d) oacc[d] *= corr;
            m = s;
        }
        float p = __expf(s - m);
        l += p;
        const float* vp = vbase + (size_t)j * DM;
        #pragma unroll
        for (int i = 0; i < 8; ++i) {
            float4 f = *(const float4*)(vp + i * 4);
            oacc[4 * i + 0] += p * f.x; oacc[4 * i + 1] += p * f.y;
            oacc[4 * i + 2] += p * f.z; oacc[4 * i + 3] += p * f.w;
        }
    }
    float inv = 1.f / l;
    float* op = out + ((size_t)(b * NQ + qi) * DM + h * 32);
    #pragma unroll
    for (int i = 0; i < 8; ++i) {
        float4 f;
        f.x = oacc[4 * i + 0] * inv; f.y = oacc[4 * i + 1] * inv;
        f.z = oacc[4 * i + 2] * inv; f.w = oacc[4 * i + 3] * inv;
        *(float4*)(op + i * 4) = f;
    }
}

// ---------------------------------------------------------------------------
// aw softmax over 16 (levels*points) per (b,q,h)
// ---------------------------------------------------------------------------
__global__ __launch_bounds__(256) void aw_softmax_kernel(float* __restrict__ aw)
{
    int t = blockIdx.x * 256 + threadIdx.x;
    if (t >= BS * NQ * 8) return;
    float* p = aw + (size_t)t * 16;
    float vals[16];
    #pragma unroll
    for (int i = 0; i < 4; ++i) {
        float4 f = *(const float4*)(p + i * 4);
        vals[4 * i + 0] = f.x; vals[4 * i + 1] = f.y;
        vals[4 * i + 2] = f.z; vals[4 * i + 3] = f.w;
    }
    float mx = vals[0];
    #pragma unroll
    for (int i = 1; i < 16; ++i) mx = fmaxf(mx, vals[i]);
    float sum = 0.f;
    #pragma unroll
    for (int i = 0; i < 16; ++i) { vals[i] = __expf(vals[i] - mx); sum += vals[i]; }
    float inv = 1.f / sum;
    #pragma unroll
    for (int i = 0; i < 4; ++i) {
        float4 f;
        f.x = vals[4 * i + 0] * inv; f.y = vals[4 * i + 1] * inv;
        f.z = vals[4 * i + 2] * inv; f.w = vals[4 * i + 3] * inv;
        *(float4*)(p + i * 4) = f;
    }
}

// ---------------------------------------------------------------------------
// Deformable sampling. One wave per (b,q): lane = h*8 + c (c = float4 chunk).
// value: (BS, LEN_V, 256); off: (BS,NQ,256) idx h*32+l*8+p*2+{x,y};
// aw: (BS,NQ,128) idx h*16+l*4+p; rbbox: (BS,NQ,4). out: (BS,NQ,256)
// ---------------------------------------------------------------------------
__global__ __launch_bounds__(256) void deform_kernel(
    const float* __restrict__ value, const float* __restrict__ off,
    const float* __restrict__ aw, const float* __restrict__ rbbox,
    float* __restrict__ dout)
{
    int t = blockIdx.x * 256 + threadIdx.x;  // bq*64 + h*8 + c
    if (t >= BS * NQ * 64) return;
    int c = t & 7;
    int h = (t >> 3) & 7;
    int bq = t >> 6;
    int b = bq / NQ;

    const int Hs[4]     = {100, 50, 25, 13};
    const int Wsz[4]    = {100, 50, 25, 13};
    const int Starts[4] = {0, 10000, 12500, 13125};

    float4 rb = *(const float4*)(rbbox + (size_t)bq * 4);
    const float* offp = off + (size_t)bq * 256 + h * 32;
    const float* awp  = aw + (size_t)bq * 128 + h * 16;
    const float* vb   = value + ((size_t)b * LEN_V) * 256 + h * 32 + c * 4;

    float4 acc = make_float4(0.f, 0.f, 0.f, 0.f);
    #pragma unroll
    for (int l = 0; l < 4; ++l) {
        const int H = Hs[l], W = Wsz[l], st = Starts[l];
        #pragma unroll
        for (int p = 0; p < 4; ++p) {
            float ox = offp[l * 8 + p * 2 + 0];
            float oy = offp[l * 8 + p * 2 + 1];
            float a_w = awp[l * 4 + p];
            float xx = (rb.x + ox * 0.125f * rb.z) * W - 0.5f;
            float yy = (rb.y + oy * 0.125f * rb.w) * H - 0.5f;
            float x0f = floorf(xx), y0f = floorf(yy);
            float fx = xx - x0f, fy = yy - y0f;
            int x0 = (int)x0f, y0 = (int)y0f;
            #pragma unroll
            for (int dy = 0; dy < 2; ++dy) {
                int yi = y0 + dy;
                float wy = dy ? fy : (1.f - fy);
                bool vy = (yi >= 0) && (yi < H);
                int yc = min(max(yi, 0), H - 1);
                #pragma unroll
                for (int dx = 0; dx < 2; ++dx) {
                    int xi = x0 + dx;
                    float wx = dx ? fx : (1.f - fx);
                    bool vx = (xi >= 0) && (xi < W);
                    int xc = min(max(xi, 0), W - 1);
                    float wgt = a_w * wy * wx * ((vx && vy) ? 1.f : 0.f);
                    float4 g = *(const float4*)(vb + (size_t)(st + yc * W + xc) * 256);
                    acc.x += wgt * g.x; acc.y += wgt * g.y;
                    acc.z += wgt * g.z; acc.w += wgt * g.w;
                }
            }
        }
    }
    *(float4*)(dout + (size_t)bq * 256 + h * 32 + c * 4) = acc;
}

// ---------------------------------------------------------------------------
// LayerNorm(x + dx) * g + b ; one wave per 256-float row, 4 rows/block
// ---------------------------------------------------------------------------
__global__ __launch_bounds__(256) void ln_kernel(
    const float* __restrict__ x, const float* __restrict__ dx,
    const float* __restrict__ g, const float* __restrict__ bt,
    float* __restrict__ out, int rows)
{
    int row = blockIdx.x * 4 + (threadIdx.x >> 6);
    if (row >= rows) return;
    int lane = threadIdx.x & 63;
    size_t base = (size_t)row * 256 + lane * 4;
    float4 xv = *(const float4*)(x + base);
    float4 dv = *(const float4*)(dx + base);
    float a0 = xv.x + dv.x, a1 = xv.y + dv.y, a2 = xv.z + dv.z, a3 = xv.w + dv.w;
    float s = a0 + a1 + a2 + a3;
    float s2 = a0 * a0 + a1 * a1 + a2 * a2 + a3 * a3;
    #pragma unroll
    for (int o = 32; o; o >>= 1) {
        s += __shfl_xor(s, o);
        s2 += __shfl_xor(s2, o);
    }
    float mean = s * (1.f / 256.f);
    float var = s2 * (1.f / 256.f) - mean * mean;
    float inv = rsqrtf(var + 1e-5f);
    float4 gv = *(const float4*)(g + lane * 4);
    float4 bv = *(const float4*)(bt + lane * 4);
    float4 r;
    r.x = (a0 - mean) * inv * gv.x + bv.x;
    r.y = (a1 - mean) * inv * gv.y + bv.y;
    r.z = (a2 - mean) * inv * gv.z + bv.z;
    r.w = (a3 - mean) * inv * gv.w + bv.w;
    *(float4*)(out + base) = r;
}

// ---------------------------------------------------------------------------
extern "C" void kernel_launch(void* const* d_in, const int* in_sizes, int n_in,
                              void* d_out, int out_size, void* d_ws, size_t ws_size,
                              hipStream_t stream)
{
    const float* embed = (const float*)d_in[0];
    const float* rbbox = (const float*)d_in[1];
    const float* feats = (const float*)d_in[2];
    const float* qpos  = (const float*)d_in[3];
    const float* Wq = (const float*)d_in[4];  const float* bq = (const float*)d_in[5];
    const float* Wk = (const float*)d_in[6];  const float* bk = (const float*)d_in[7];
    const float* Wv = (const float*)d_in[8];  const float* bv = (const float*)d_in[9];
    const float* Wo = (const float*)d_in[10]; const float* bo = (const float*)d_in[11];
    const float* g1 = (const float*)d_in[12]; const float* b1 = (const float*)d_in[13];
    const float* Wval = (const float*)d_in[14]; const float* bval = (const float*)d_in[15];
    const float* Woff = (const float*)d_in[16]; const float* boff = (const float*)d_in[17];
    const float* Waw  = (const float*)d_in[18]; const float* baw  = (const float*)d_in[19];
    const float* Wop  = (const float*)d_in[20]; const float* bop  = (const float*)d_in[21];
    const float* g2 = (const float*)d_in[22]; const float* b2 = (const float*)d_in[23];
    const float* W1 = (const float*)d_in[24]; const float* bf1 = (const float*)d_in[25];
    const float* W2 = (const float*)d_in[26]; const float* bf2 = (const float*)d_in[27];
    const float* g3 = (const float*)d_in[28]; const float* b3 = (const float*)d_in[29];

    const int M = BS * NQ;                 // 7200
    const int MV = BS * LEN_V;             // 106352
    const size_t E = (size_t)M * DM;       // 1,843,200 floats
    const size_t VAL = (size_t)MV * DM;    // 27,226,112 floats

    float* ws = (float*)d_ws;
    float* valueb = ws;                    // VAL
    float* qb   = ws + VAL;                // E
    float* kb   = qb + E;                  // E
    float* vbuf = kb + E;                  // E
    float* attb = vbuf + E;                // E
    float* e1b  = attb + E;                // E
    // aliases (sequentially safe):
    float* sab   = qb;      // Wo output
    float* offb  = kb;      // sampling offsets
    float* awbuf = vbuf;    // attention weights (N=128)
    float* doutb = attb;    // deformable output
    float* cab   = qb;      // Wop output
    float* e2b   = kb;      // embed after LN2
    float* ffhb  = valueb;  // FFN hidden (7200x1024)
    float* ffb   = vbuf;    // FFN output

    dim3 blk(256);
    auto gg = [](int m, int n) { return dim3((m + 63) / 64, n / 64); };

    // 1-3: q, k, v projections
    gemm_kernel<<<gg(M, 256), blk, 0, stream>>>(embed, qpos, Wq, bq, qb, M, 256, 256, 0);
    gemm_kernel<<<gg(M, 256), blk, 0, stream>>>(embed, qpos, Wk, bk, kb, M, 256, 256, 0);
    gemm_kernel<<<gg(M, 256), blk, 0, stream>>>(embed, nullptr, Wv, bv, vbuf, M, 256, 256, 0);
    // 4: self-attention
    attn_kernel<<<dim3((BS * 8 * NQ + 255) / 256), blk, 0, stream>>>(qb, kb, vbuf, attb);
    // 5: output projection
    gemm_kernel<<<gg(M, 256), blk, 0, stream>>>(attb, nullptr, Wo, bo, sab, M, 256, 256, 0);
    // 6: LN1
    ln_kernel<<<dim3((M + 3) / 4), blk, 0, stream>>>(embed, sab, g1, b1, e1b, M);
    // 7: value projection (big GEMM)
    gemm_kernel<<<gg(MV, 256), blk, 0, stream>>>(feats, nullptr, Wval, bval, valueb, MV, 256, 256, 0);
    // 8-9: offsets + attention-weight logits (query = e1 + qpos fused)
    gemm_kernel<<<gg(M, 256), blk, 0, stream>>>(e1b, qpos, Woff, boff, offb, M, 256, 256, 0);
    gemm_kernel<<<gg(M, 128), blk, 0, stream>>>(e1b, qpos, Waw, baw, awbuf, M, 128, 256, 0);
    // 10: softmax over 16
    aw_softmax_kernel<<<dim3((BS * NQ * 8 + 255) / 256), blk, 0, stream>>>(awbuf);
    // 11: deformable sampling
    deform_kernel<<<dim3((BS * NQ * 64 + 255) / 256), blk, 0, stream>>>(valueb, offb, awbuf, rbbox, doutb);
    // 12: output projection of deformable attention
    gemm_kernel<<<gg(M, 256), blk, 0, stream>>>(doutb, nullptr, Wop, bop, cab, M, 256, 256, 0);
    // 13: LN2
    ln_kernel<<<dim3((M + 3) / 4), blk, 0, stream>>>(e1b, cab, g2, b2, e2b, M);
    // 14-15: FFN
    gemm_kernel<<<gg(M, 1024), blk, 0, stream>>>(e2b, nullptr, W1, bf1, ffhb, M, 1024, 256, 1);
    gemm_kernel<<<gg(M, 256), blk, 0, stream>>>(ffhb, nullptr, W2, bf2, ffb, M, 256, 1024, 0);
    // 16: LN3 -> out
    ln_kernel<<<dim3((M + 3) / 4), blk, 0, stream>>>(e2b, ffb, g3, b3, (float*)d_out, M);
}

// Round 2
// 995.623 us; speedup vs baseline: 1.1809x; 1.1809x over previous
//
#include <hip/hip_runtime.h>
#include <hip/hip_bf16.h>
#include <cstddef>

#define BS 8
#define NQ 900
#define DM 256
#define LEN_V 13294
#define KSPLIT 8
#define KCHUNK 113   // ceil(900/8)
#define PSTRIDE 40   // floats per partial record: o[32], m@32, l@33, pad->40 (160B aligned)

// ---------------------------------------------------------------------------
// Generic tiled fp32 GEMM: C[M,N] = (A [+ A2]) @ B[K,N] + bias, optional relu
// ---------------------------------------------------------------------------
__global__ __launch_bounds__(256) void gemm_kernel(
    const float* __restrict__ A, const float* __restrict__ A2,
    const float* __restrict__ B, const float* __restrict__ bias,
    float* __restrict__ C, int M, int N, int K, int relu)
{
    __shared__ float As[16][68];
    __shared__ float Bs[16][68];
    const int tid = threadIdx.x;
    const int row0 = blockIdx.x * 64;
    const int col0 = blockIdx.y * 64;
    const int ty = tid >> 4;
    const int tx = tid & 15;
    const int arow = tid >> 2;
    const int acol = (tid & 3) * 4;
    const int brow = tid >> 4;
    const int bcol = (tid & 15) * 4;

    float acc[4][4] = {};

    for (int k0 = 0; k0 < K; k0 += 16) {
        {
            int r = row0 + arow;
            float4 a = make_float4(0.f, 0.f, 0.f, 0.f);
            if (r < M) {
                a = *(const float4*)(A + (size_t)r * K + k0 + acol);
                if (A2) {
                    float4 a2 = *(const float4*)(A2 + (size_t)r * K + k0 + acol);
                    a.x += a2.x; a.y += a2.y; a.z += a2.z; a.w += a2.w;
                }
            }
            As[acol + 0][arow] = a.x;
            As[acol + 1][arow] = a.y;
            As[acol + 2][arow] = a.z;
            As[acol + 3][arow] = a.w;
        }
        {
            float4 b = *(const float4*)(B + (size_t)(k0 + brow) * N + col0 + bcol);
            *(float4*)&Bs[brow][bcol] = b;
        }
        __syncthreads();
        #pragma unroll
        for (int kk = 0; kk < 16; ++kk) {
            float a[4], b[4];
            #pragma unroll
            for (int i = 0; i < 4; ++i) a[i] = As[kk][ty * 4 + i];
            #pragma unroll
            for (int j = 0; j < 4; ++j) b[j] = Bs[kk][tx * 4 + j];
            #pragma unroll
            for (int i = 0; i < 4; ++i)
                #pragma unroll
                for (int j = 0; j < 4; ++j)
                    acc[i][j] += a[i] * b[j];
        }
        __syncthreads();
    }

    const float4 bv = *(const float4*)(bias + col0 + tx * 4);
    #pragma unroll
    for (int i = 0; i < 4; ++i) {
        int r = row0 + ty * 4 + i;
        if (r >= M) continue;
        float4 o;
        o.x = acc[i][0] + bv.x;
        o.y = acc[i][1] + bv.y;
        o.z = acc[i][2] + bv.z;
        o.w = acc[i][3] + bv.w;
        if (relu) {
            o.x = fmaxf(o.x, 0.f); o.y = fmaxf(o.y, 0.f);
            o.z = fmaxf(o.z, 0.f); o.w = fmaxf(o.w, 0.f);
        }
        *(float4*)(C + (size_t)r * N + col0 + tx * 4) = o;
    }
}

// ---------------------------------------------------------------------------
// Self-attention partial: one thread per (b,h,ks,qi); online softmax over
// keys [ks*KCHUNK, min(900,(ks+1)*KCHUNK)). Writes (o[32],m,l) partial.
// ---------------------------------------------------------------------------
__global__ __launch_bounds__(256) void attn_partial_kernel(
    const float* __restrict__ q, const float* __restrict__ k,
    const float* __restrict__ v, float* __restrict__ part)
{
    int t = blockIdx.x * 256 + threadIdx.x;   // ((bh*KSPLIT + ks)*NQ + qi)
    if (t >= BS * 8 * KSPLIT * NQ) return;
    int qi = t % NQ;
    int rest = t / NQ;
    int ks = rest & (KSPLIT - 1);
    int bh = rest / KSPLIT;
    int h = bh & 7, b = bh >> 3;
    const float scale = 0.17677669529663687f; // 1/sqrt(32)

    float qv[32];
    {
        const float* qp = q + ((size_t)(b * NQ + qi) * DM + h * 32);
        #pragma unroll
        for (int i = 0; i < 8; ++i) {
            float4 f = *(const float4*)(qp + i * 4);
            qv[4 * i + 0] = f.x * scale; qv[4 * i + 1] = f.y * scale;
            qv[4 * i + 2] = f.z * scale; qv[4 * i + 3] = f.w * scale;
        }
    }
    float m = -3.0e38f, l = 0.f;
    float oacc[32];
    #pragma unroll
    for (int d = 0; d < 32; ++d) oacc[d] = 0.f;

    const int j0 = ks * KCHUNK;
    const int j1 = min(NQ, j0 + KCHUNK);
    const float* kbase = k + ((size_t)b * NQ) * DM + h * 32;
    const float* vbase = v + ((size_t)b * NQ) * DM + h * 32;
    for (int j = j0; j < j1; ++j) {
        const float* kp = kbase + (size_t)j * DM;
        float s = 0.f;
        #pragma unroll
        for (int i = 0; i < 8; ++i) {
            float4 f = *(const float4*)(kp + i * 4);
            s += qv[4 * i + 0] * f.x + qv[4 * i + 1] * f.y
               + qv[4 * i + 2] * f.z + qv[4 * i + 3] * f.w;
        }
        if (s > m) {
            float corr = __expf(m - s);
            l *= corr;
            #pragma unroll
            for (int d = 0; d < 32; ++d) oacc[d] *= corr;
            m = s;
        }
        float p = __expf(s - m);
        l += p;
        const float* vp = vbase + (size_t)j * DM;
        #pragma unroll
        for (int i = 0; i < 8; ++i) {
            float4 f = *(const float4*)(vp + i * 4);
            oacc[4 * i + 0] += p * f.x; oacc[4 * i + 1] += p * f.y;
            oacc[4 * i + 2] += p * f.z; oacc[4 * i + 3] += p * f.w;
        }
    }
    float* pp = part + ((size_t)(bh * NQ + qi) * KSPLIT + ks) * PSTRIDE;
    #pragma unroll
    for (int i = 0; i < 8; ++i) {
        float4 f;
        f.x = oacc[4 * i + 0]; f.y = oacc[4 * i + 1];
        f.z = oacc[4 * i + 2]; f.w = oacc[4 * i + 3];
        *(float4*)(pp + i * 4) = f;
    }
    pp[32] = m;
    pp[33] = l;
}

// ---------------------------------------------------------------------------
// Combine KSPLIT partials -> out (b, qi, 256) at head offset
// ---------------------------------------------------------------------------
__global__ __launch_bounds__(256) void attn_combine_kernel(
    const float* __restrict__ part, float* __restrict__ out)
{
    int t = blockIdx.x * 256 + threadIdx.x;   // bh*NQ + qi
    if (t >= BS * 8 * NQ) return;
    int qi = t % NQ;
    int bh = t / NQ;
    int h = bh & 7, b = bh >> 3;

    const float* base = part + (size_t)t * KSPLIT * PSTRIDE;
    float M = -3.0e38f;
    #pragma unroll
    for (int ks = 0; ks < KSPLIT; ++ks)
        M = fmaxf(M, base[ks * PSTRIDE + 32]);
    float L = 0.f;
    float O[32];
    #pragma unroll
    for (int d = 0; d < 32; ++d) O[d] = 0.f;
    #pragma unroll
    for (int ks = 0; ks < KSPLIT; ++ks) {
        const float* pp = base + ks * PSTRIDE;
        float c = __expf(pp[32] - M);
        L += pp[33] * c;
        #pragma unroll
        for (int i = 0; i < 8; ++i) {
            float4 f = *(const float4*)(pp + i * 4);
            O[4 * i + 0] += f.x * c; O[4 * i + 1] += f.y * c;
            O[4 * i + 2] += f.z * c; O[4 * i + 3] += f.w * c;
        }
    }
    float inv = 1.f / L;
    float* op = out + ((size_t)(b * NQ + qi) * DM + h * 32);
    #pragma unroll
    for (int i = 0; i < 8; ++i) {
        float4 f;
        f.x = O[4 * i + 0] * inv; f.y = O[4 * i + 1] * inv;
        f.z = O[4 * i + 2] * inv; f.w = O[4 * i + 3] * inv;
        *(float4*)(op + i * 4) = f;
    }
}

// ---------------------------------------------------------------------------
// aw softmax over 16 (levels*points) per (b,q,h)
// ---------------------------------------------------------------------------
__global__ __launch_bounds__(256) void aw_softmax_kernel(float* __restrict__ aw)
{
    int t = blockIdx.x * 256 + threadIdx.x;
    if (t >= BS * NQ * 8) return;
    float* p = aw + (size_t)t * 16;
    float vals[16];
    #pragma unroll
    for (int i = 0; i < 4; ++i) {
        float4 f = *(const float4*)(p + i * 4);
        vals[4 * i + 0] = f.x; vals[4 * i + 1] = f.y;
        vals[4 * i + 2] = f.z; vals[4 * i + 3] = f.w;
    }
    float mx = vals[0];
    #pragma unroll
    for (int i = 1; i < 16; ++i) mx = fmaxf(mx, vals[i]);
    float sum = 0.f;
    #pragma unroll
    for (int i = 0; i < 16; ++i) { vals[i] = __expf(vals[i] - mx); sum += vals[i]; }
    float inv = 1.f / sum;
    #pragma unroll
    for (int i = 0; i < 4; ++i) {
        float4 f;
        f.x = vals[4 * i + 0] * inv; f.y = vals[4 * i + 1] * inv;
        f.z = vals[4 * i + 2] * inv; f.w = vals[4 * i + 3] * inv;
        *(float4*)(p + i * 4) = f;
    }
}

// ---------------------------------------------------------------------------
// Deformable sampling. lane = h*8 + c (c = float4 chunk).
// ---------------------------------------------------------------------------
__global__ __launch_bounds__(256) void deform_kernel(
    const float* __restrict__ value, const float* __restrict__ off,
    const float* __restrict__ aw, const float* __restrict__ rbbox,
    float* __restrict__ dout)
{
    int t = blockIdx.x * 256 + threadIdx.x;  // bq*64 + h*8 + c
    if (t >= BS * NQ * 64) return;
    int c = t & 7;
    int h = (t >> 3) & 7;
    int bq = t >> 6;
    int b = bq / NQ;

    const int Hs[4]     = {100, 50, 25, 13};
    const int Wsz[4]    = {100, 50, 25, 13};
    const int Starts[4] = {0, 10000, 12500, 13125};

    float4 rb = *(const float4*)(rbbox + (size_t)bq * 4);
    const float* offp = off + (size_t)bq * 256 + h * 32;
    const float* awp  = aw + (size_t)bq * 128 + h * 16;
    const float* vb   = value + ((size_t)b * LEN_V) * 256 + h * 32 + c * 4;

    float4 acc = make_float4(0.f, 0.f, 0.f, 0.f);
    #pragma unroll
    for (int l = 0; l < 4; ++l) {
        const int H = Hs[l], W = Wsz[l], st = Starts[l];
        #pragma unroll
        for (int p = 0; p < 4; ++p) {
            float ox = offp[l * 8 + p * 2 + 0];
            float oy = offp[l * 8 + p * 2 + 1];
            float a_w = awp[l * 4 + p];
            float xx = (rb.x + ox * 0.125f * rb.z) * W - 0.5f;
            float yy = (rb.y + oy * 0.125f * rb.w) * H - 0.5f;
            float x0f = floorf(xx), y0f = floorf(yy);
            float fx = xx - x0f, fy = yy - y0f;
            int x0 = (int)x0f, y0 = (int)y0f;
            #pragma unroll
            for (int dy = 0; dy < 2; ++dy) {
                int yi = y0 + dy;
                float wy = dy ? fy : (1.f - fy);
                bool vy = (yi >= 0) && (yi < H);
                int yc = min(max(yi, 0), H - 1);
                #pragma unroll
                for (int dx = 0; dx < 2; ++dx) {
                    int xi = x0 + dx;
                    float wx = dx ? fx : (1.f - fx);
                    bool vx = (xi >= 0) && (xi < W);
                    int xc = min(max(xi, 0), W - 1);
                    float wgt = a_w * wy * wx * ((vx && vy) ? 1.f : 0.f);
                    float4 g = *(const float4*)(vb + (size_t)(st + yc * W + xc) * 256);
                    acc.x += wgt * g.x; acc.y += wgt * g.y;
                    acc.z += wgt * g.z; acc.w += wgt * g.w;
                }
            }
        }
    }
    *(float4*)(dout + (size_t)bq * 256 + h * 32 + c * 4) = acc;
}

// ---------------------------------------------------------------------------
// LayerNorm(x + dx) * g + b
// ---------------------------------------------------------------------------
__global__ __launch_bounds__(256) void ln_kernel(
    const float* __restrict__ x, const float* __restrict__ dx,
    const float* __restrict__ g, const float* __restrict__ bt,
    float* __restrict__ out, int rows)
{
    int row = blockIdx.x * 4 + (threadIdx.x >> 6);
    if (row >= rows) return;
    int lane = threadIdx.x & 63;
    size_t base = (size_t)row * 256 + lane * 4;
    float4 xv = *(const float4*)(x + base);
    float4 dv = *(const float4*)(dx + base);
    float a0 = xv.x + dv.x, a1 = xv.y + dv.y, a2 = xv.z + dv.z, a3 = xv.w + dv.w;
    float s = a0 + a1 + a2 + a3;
    float s2 = a0 * a0 + a1 * a1 + a2 * a2 + a3 * a3;
    #pragma unroll
    for (int o = 32; o; o >>= 1) {
        s += __shfl_xor(s, o);
        s2 += __shfl_xor(s2, o);
    }
    float mean = s * (1.f / 256.f);
    float var = s2 * (1.f / 256.f) - mean * mean;
    float inv = rsqrtf(var + 1e-5f);
    float4 gv = *(const float4*)(g + lane * 4);
    float4 bv = *(const float4*)(bt + lane * 4);
    float4 r;
    r.x = (a0 - mean) * inv * gv.x + bv.x;
    r.y = (a1 - mean) * inv * gv.y + bv.y;
    r.z = (a2 - mean) * inv * gv.z + bv.z;
    r.w = (a3 - mean) * inv * gv.w + bv.w;
    *(float4*)(out + base) = r;
}

// ---------------------------------------------------------------------------
extern "C" void kernel_launch(void* const* d_in, const int* in_sizes, int n_in,
                              void* d_out, int out_size, void* d_ws, size_t ws_size,
                              hipStream_t stream)
{
    const float* embed = (const float*)d_in[0];
    const float* rbbox = (const float*)d_in[1];
    const float* feats = (const float*)d_in[2];
    const float* qpos  = (const float*)d_in[3];
    const float* Wq = (const float*)d_in[4];  const float* bq = (const float*)d_in[5];
    const float* Wk = (const float*)d_in[6];  const float* bk = (const float*)d_in[7];
    const float* Wv = (const float*)d_in[8];  const float* bv = (const float*)d_in[9];
    const float* Wo = (const float*)d_in[10]; const float* bo = (const float*)d_in[11];
    const float* g1 = (const float*)d_in[12]; const float* b1 = (const float*)d_in[13];
    const float* Wval = (const float*)d_in[14]; const float* bval = (const float*)d_in[15];
    const float* Woff = (const float*)d_in[16]; const float* boff = (const float*)d_in[17];
    const float* Waw  = (const float*)d_in[18]; const float* baw  = (const float*)d_in[19];
    const float* Wop  = (const float*)d_in[20]; const float* bop  = (const float*)d_in[21];
    const float* g2 = (const float*)d_in[22]; const float* b2 = (const float*)d_in[23];
    const float* W1 = (const float*)d_in[24]; const float* bf1 = (const float*)d_in[25];
    const float* W2 = (const float*)d_in[26]; const float* bf2 = (const float*)d_in[27];
    const float* g3 = (const float*)d_in[28]; const float* b3 = (const float*)d_in[29];

    const int M = BS * NQ;                 // 7200
    const int MV = BS * LEN_V;             // 106352
    const size_t E = (size_t)M * DM;       // 1,843,200 floats
    const size_t VAL = (size_t)MV * DM;    // 27,226,112 floats

    float* ws = (float*)d_ws;
    float* valueb = ws;                    // VAL floats
    float* qb   = ws + VAL;                // E
    float* kb   = qb + E;                  // E
    float* vbuf = kb + E;                  // E
    float* attb = vbuf + E;                // E
    float* e1b  = attb + E;                // E
    // attention partials alias the (not-yet-written) value buffer:
    float* partb = valueb;                 // 57600*8*40 = 18.43M floats < VAL
    // aliases (sequentially safe):
    float* sab   = qb;      // Wo output
    float* offb  = kb;      // sampling offsets
    float* awbuf = vbuf;    // attention weights (N=128)
    float* doutb = attb;    // deformable output
    float* cab   = qb;      // Wop output
    float* e2b   = kb;      // embed after LN2
    float* ffhb  = valueb;  // FFN hidden (7200x1024)
    float* ffb   = vbuf;    // FFN output

    dim3 blk(256);
    auto gg = [](int m, int n) { return dim3((m + 63) / 64, n / 64); };

    // 1-3: q, k, v projections
    gemm_kernel<<<gg(M, 256), blk, 0, stream>>>(embed, qpos, Wq, bq, qb, M, 256, 256, 0);
    gemm_kernel<<<gg(M, 256), blk, 0, stream>>>(embed, qpos, Wk, bk, kb, M, 256, 256, 0);
    gemm_kernel<<<gg(M, 256), blk, 0, stream>>>(embed, nullptr, Wv, bv, vbuf, M, 256, 256, 0);
    // 4: self-attention (key-split partials + combine)
    {
        int nthr = BS * 8 * KSPLIT * NQ;   // 460800
        attn_partial_kernel<<<dim3((nthr + 255) / 256), blk, 0, stream>>>(qb, kb, vbuf, partb);
        attn_combine_kernel<<<dim3((BS * 8 * NQ + 255) / 256), blk, 0, stream>>>(partb, attb);
    }
    // 5: output projection
    gemm_kernel<<<gg(M, 256), blk, 0, stream>>>(attb, nullptr, Wo, bo, sab, M, 256, 256, 0);
    // 6: LN1
    ln_kernel<<<dim3((M + 3) / 4), blk, 0, stream>>>(embed, sab, g1, b1, e1b, M);
    // 7: value projection (big GEMM) -- overwrites partials (dead now)
    gemm_kernel<<<gg(MV, 256), blk, 0, stream>>>(feats, nullptr, Wval, bval, valueb, MV, 256, 256, 0);
    // 8-9: offsets + attention-weight logits (query = e1 + qpos fused)
    gemm_kernel<<<gg(M, 256), blk, 0, stream>>>(e1b, qpos, Woff, boff, offb, M, 256, 256, 0);
    gemm_kernel<<<gg(M, 128), blk, 0, stream>>>(e1b, qpos, Waw, baw, awbuf, M, 128, 256, 0);
    // 10: softmax over 16
    aw_softmax_kernel<<<dim3((BS * NQ * 8 + 255) / 256), blk, 0, stream>>>(awbuf);
    // 11: deformable sampling
    deform_kernel<<<dim3((BS * NQ * 64 + 255) / 256), blk, 0, stream>>>(valueb, offb, awbuf, rbbox, doutb);
    // 12: output projection of deformable attention
    gemm_kernel<<<gg(M, 256), blk, 0, stream>>>(doutb, nullptr, Wop, bop, cab, M, 256, 256, 0);
    // 13: LN2
    ln_kernel<<<dim3((M + 3) / 4), blk, 0, stream>>>(e1b, cab, g2, b2, e2b, M);
    // 14-15: FFN
    gemm_kernel<<<gg(M, 1024), blk, 0, stream>>>(e2b, nullptr, W1, bf1, ffhb, M, 1024, 256, 1);
    gemm_kernel<<<gg(M, 256), blk, 0, stream>>>(ffhb, nullptr, W2, bf2, ffb, M, 256, 1024, 0);
    // 16: LN3 -> out
    ln_kernel<<<dim3((M + 3) / 4), blk, 0, stream>>>(e2b, ffb, g3, b3, (float*)d_out, M);
}

// Round 3
// 740.734 us; speedup vs baseline: 1.5873x; 1.3441x over previous
//
#include <hip/hip_runtime.h>
#include <hip/hip_bf16.h>
#include <cstddef>

#define BS 8
#define NQ 900
#define DM 256
#define LEN_V 13294
#define KSPLIT 4
#define KCHUNK 225   // 900/4
#define KV_STAGE 64
#define PSTRIDE 40   // floats per partial record: o[32], m@32, l@33, pad->40

// ---------------------------------------------------------------------------
// Generic tiled fp32 GEMM: C[M,N] = (A [+ A2]) @ B[K,N] + bias, optional relu
// ---------------------------------------------------------------------------
__global__ __launch_bounds__(256) void gemm_kernel(
    const float* __restrict__ A, const float* __restrict__ A2,
    const float* __restrict__ B, const float* __restrict__ bias,
    float* __restrict__ C, int M, int N, int K, int relu)
{
    __shared__ float As[16][68];
    __shared__ float Bs[16][68];
    const int tid = threadIdx.x;
    const int row0 = blockIdx.x * 64;
    const int col0 = blockIdx.y * 64;
    const int ty = tid >> 4;
    const int tx = tid & 15;
    const int arow = tid >> 2;
    const int acol = (tid & 3) * 4;
    const int brow = tid >> 4;
    const int bcol = (tid & 15) * 4;

    float acc[4][4] = {};

    for (int k0 = 0; k0 < K; k0 += 16) {
        {
            int r = row0 + arow;
            float4 a = make_float4(0.f, 0.f, 0.f, 0.f);
            if (r < M) {
                a = *(const float4*)(A + (size_t)r * K + k0 + acol);
                if (A2) {
                    float4 a2 = *(const float4*)(A2 + (size_t)r * K + k0 + acol);
                    a.x += a2.x; a.y += a2.y; a.z += a2.z; a.w += a2.w;
                }
            }
            As[acol + 0][arow] = a.x;
            As[acol + 1][arow] = a.y;
            As[acol + 2][arow] = a.z;
            As[acol + 3][arow] = a.w;
        }
        {
            float4 b = *(const float4*)(B + (size_t)(k0 + brow) * N + col0 + bcol);
            *(float4*)&Bs[brow][bcol] = b;
        }
        __syncthreads();
        #pragma unroll
        for (int kk = 0; kk < 16; ++kk) {
            float a[4], b[4];
            #pragma unroll
            for (int i = 0; i < 4; ++i) a[i] = As[kk][ty * 4 + i];
            #pragma unroll
            for (int j = 0; j < 4; ++j) b[j] = Bs[kk][tx * 4 + j];
            #pragma unroll
            for (int i = 0; i < 4; ++i)
                #pragma unroll
                for (int j = 0; j < 4; ++j)
                    acc[i][j] += a[i] * b[j];
        }
        __syncthreads();
    }

    const float4 bv = *(const float4*)(bias + col0 + tx * 4);
    #pragma unroll
    for (int i = 0; i < 4; ++i) {
        int r = row0 + ty * 4 + i;
        if (r >= M) continue;
        float4 o;
        o.x = acc[i][0] + bv.x;
        o.y = acc[i][1] + bv.y;
        o.z = acc[i][2] + bv.z;
        o.w = acc[i][3] + bv.w;
        if (relu) {
            o.x = fmaxf(o.x, 0.f); o.y = fmaxf(o.y, 0.f);
            o.z = fmaxf(o.z, 0.f); o.w = fmaxf(o.w, 0.f);
        }
        *(float4*)(C + (size_t)r * N + col0 + tx * 4) = o;
    }
}

// ---------------------------------------------------------------------------
// Flash-style self-attention partial with LDS-staged K/V.
// grid: (64 bh, 4 qblk, KSPLIT ks). Block 256 threads, one q-row per thread.
// Keys [ks*KCHUNK, ks*KCHUNK+KCHUNK) staged 64 at a time into LDS.
// Writes partial (o[32], m, l) records.
// ---------------------------------------------------------------------------
__global__ __launch_bounds__(256) void attn_flash_kernel(
    const float* __restrict__ q, const float* __restrict__ k,
    const float* __restrict__ v, float* __restrict__ part)
{
    const int bh = blockIdx.x;
    const int h = bh & 7, b = bh >> 3;
    const int qi = blockIdx.y * 256 + threadIdx.x;
    const int ks = blockIdx.z;
    const bool active = qi < NQ;
    const int qic = active ? qi : NQ - 1;

    __shared__ float ksh[KV_STAGE][32];
    __shared__ float vsh[KV_STAGE][32];

    const float scale = 0.17677669529663687f; // 1/sqrt(32)
    float qv[32];
    {
        const float* qp = q + ((size_t)(b * NQ + qic) * DM + h * 32);
        #pragma unroll
        for (int i = 0; i < 8; ++i) {
            float4 f = *(const float4*)(qp + i * 4);
            qv[4 * i + 0] = f.x * scale; qv[4 * i + 1] = f.y * scale;
            qv[4 * i + 2] = f.z * scale; qv[4 * i + 3] = f.w * scale;
        }
    }

    float m = -3.0e38f, l = 0.f;
    float oacc[32];
    #pragma unroll
    for (int d = 0; d < 32; ++d) oacc[d] = 0.f;

    const int j0 = ks * KCHUNK;
    const int j1 = min(NQ, j0 + KCHUNK);
    const int srow = threadIdx.x >> 2;        // 0..63
    const int scol = (threadIdx.x & 3) * 8;   // 0,8,16,24

    for (int jb = j0; jb < j1; jb += KV_STAGE) {
        const int cnt = min(KV_STAGE, j1 - jb);
        __syncthreads();   // previous stage fully consumed
        if (srow < cnt) {
            const float* kp = k + ((size_t)(b * NQ + jb + srow) * DM + h * 32 + scol);
            const float* vp = v + ((size_t)(b * NQ + jb + srow) * DM + h * 32 + scol);
            *(float4*)&ksh[srow][scol]     = *(const float4*)kp;
            *(float4*)&ksh[srow][scol + 4] = *(const float4*)(kp + 4);
            *(float4*)&vsh[srow][scol]     = *(const float4*)vp;
            *(float4*)&vsh[srow][scol + 4] = *(const float4*)(vp + 4);
        }
        __syncthreads();

        const int full = cnt & ~7;
        for (int jj = 0; jj < full; jj += 8) {
            float s[8];
            #pragma unroll
            for (int u = 0; u < 8; ++u) {
                float acc = 0.f;
                #pragma unroll
                for (int i = 0; i < 8; ++i) {
                    float4 f = *(const float4*)&ksh[jj + u][i * 4];
                    acc += qv[4 * i + 0] * f.x + qv[4 * i + 1] * f.y
                         + qv[4 * i + 2] * f.z + qv[4 * i + 3] * f.w;
                }
                s[u] = acc;
            }
            float mc = s[0];
            #pragma unroll
            for (int u = 1; u < 8; ++u) mc = fmaxf(mc, s[u]);
            if (mc > m) {
                float corr = __expf(m - mc);
                l *= corr;
                #pragma unroll
                for (int d = 0; d < 32; ++d) oacc[d] *= corr;
                m = mc;
            }
            #pragma unroll
            for (int u = 0; u < 8; ++u) {
                float p = __expf(s[u] - m);
                l += p;
                #pragma unroll
                for (int i = 0; i < 8; ++i) {
                    float4 f = *(const float4*)&vsh[jj + u][i * 4];
                    oacc[4 * i + 0] += p * f.x; oacc[4 * i + 1] += p * f.y;
                    oacc[4 * i + 2] += p * f.z; oacc[4 * i + 3] += p * f.w;
                }
            }
        }
        for (int jj = full; jj < cnt; ++jj) {
            float sv = 0.f;
            #pragma unroll
            for (int i = 0; i < 8; ++i) {
                float4 f = *(const float4*)&ksh[jj][i * 4];
                sv += qv[4 * i + 0] * f.x + qv[4 * i + 1] * f.y
                    + qv[4 * i + 2] * f.z + qv[4 * i + 3] * f.w;
            }
            if (sv > m) {
                float corr = __expf(m - sv);
                l *= corr;
                #pragma unroll
                for (int d = 0; d < 32; ++d) oacc[d] *= corr;
                m = sv;
            }
            float p = __expf(sv - m);
            l += p;
            #pragma unroll
            for (int i = 0; i < 8; ++i) {
                float4 f = *(const float4*)&vsh[jj][i * 4];
                oacc[4 * i + 0] += p * f.x; oacc[4 * i + 1] += p * f.y;
                oacc[4 * i + 2] += p * f.z; oacc[4 * i + 3] += p * f.w;
            }
        }
    }

    if (active) {
        float* pp = part + ((size_t)(bh * NQ + qi) * KSPLIT + ks) * PSTRIDE;
        #pragma unroll
        for (int i = 0; i < 8; ++i) {
            float4 f;
            f.x = oacc[4 * i + 0]; f.y = oacc[4 * i + 1];
            f.z = oacc[4 * i + 2]; f.w = oacc[4 * i + 3];
            *(float4*)(pp + i * 4) = f;
        }
        pp[32] = m;
        pp[33] = l;
    }
}

// ---------------------------------------------------------------------------
// Combine KSPLIT partials -> out (b, qi, 256) at head offset
// ---------------------------------------------------------------------------
__global__ __launch_bounds__(256) void attn_combine_kernel(
    const float* __restrict__ part, float* __restrict__ out)
{
    int t = blockIdx.x * 256 + threadIdx.x;   // bh*NQ + qi
    if (t >= BS * 8 * NQ) return;
    int qi = t % NQ;
    int bh = t / NQ;
    int h = bh & 7, b = bh >> 3;

    const float* base = part + (size_t)t * KSPLIT * PSTRIDE;
    float M = -3.0e38f;
    #pragma unroll
    for (int ks = 0; ks < KSPLIT; ++ks)
        M = fmaxf(M, base[ks * PSTRIDE + 32]);
    float L = 0.f;
    float O[32];
    #pragma unroll
    for (int d = 0; d < 32; ++d) O[d] = 0.f;
    #pragma unroll
    for (int ks = 0; ks < KSPLIT; ++ks) {
        const float* pp = base + ks * PSTRIDE;
        float c = __expf(pp[32] - M);
        L += pp[33] * c;
        #pragma unroll
        for (int i = 0; i < 8; ++i) {
            float4 f = *(const float4*)(pp + i * 4);
            O[4 * i + 0] += f.x * c; O[4 * i + 1] += f.y * c;
            O[4 * i + 2] += f.z * c; O[4 * i + 3] += f.w * c;
        }
    }
    float inv = 1.f / L;
    float* op = out + ((size_t)(b * NQ + qi) * DM + h * 32);
    #pragma unroll
    for (int i = 0; i < 8; ++i) {
        float4 f;
        f.x = O[4 * i + 0] * inv; f.y = O[4 * i + 1] * inv;
        f.z = O[4 * i + 2] * inv; f.w = O[4 * i + 3] * inv;
        *(float4*)(op + i * 4) = f;
    }
}

// ---------------------------------------------------------------------------
// aw softmax over 16 (levels*points) per (b,q,h)
// ---------------------------------------------------------------------------
__global__ __launch_bounds__(256) void aw_softmax_kernel(float* __restrict__ aw)
{
    int t = blockIdx.x * 256 + threadIdx.x;
    if (t >= BS * NQ * 8) return;
    float* p = aw + (size_t)t * 16;
    float vals[16];
    #pragma unroll
    for (int i = 0; i < 4; ++i) {
        float4 f = *(const float4*)(p + i * 4);
        vals[4 * i + 0] = f.x; vals[4 * i + 1] = f.y;
        vals[4 * i + 2] = f.z; vals[4 * i + 3] = f.w;
    }
    float mx = vals[0];
    #pragma unroll
    for (int i = 1; i < 16; ++i) mx = fmaxf(mx, vals[i]);
    float sum = 0.f;
    #pragma unroll
    for (int i = 0; i < 16; ++i) { vals[i] = __expf(vals[i] - mx); sum += vals[i]; }
    float inv = 1.f / sum;
    #pragma unroll
    for (int i = 0; i < 4; ++i) {
        float4 f;
        f.x = vals[4 * i + 0] * inv; f.y = vals[4 * i + 1] * inv;
        f.z = vals[4 * i + 2] * inv; f.w = vals[4 * i + 3] * inv;
        *(float4*)(p + i * 4) = f;
    }
}

// ---------------------------------------------------------------------------
// Deformable sampling. lane = h*8 + c (c = float4 chunk).
// ---------------------------------------------------------------------------
__global__ __launch_bounds__(256) void deform_kernel(
    const float* __restrict__ value, const float* __restrict__ off,
    const float* __restrict__ aw, const float* __restrict__ rbbox,
    float* __restrict__ dout)
{
    int t = blockIdx.x * 256 + threadIdx.x;  // bq*64 + h*8 + c
    if (t >= BS * NQ * 64) return;
    int c = t & 7;
    int h = (t >> 3) & 7;
    int bq = t >> 6;
    int b = bq / NQ;

    const int Hs[4]     = {100, 50, 25, 13};
    const int Wsz[4]    = {100, 50, 25, 13};
    const int Starts[4] = {0, 10000, 12500, 13125};

    float4 rb = *(const float4*)(rbbox + (size_t)bq * 4);
    const float* offp = off + (size_t)bq * 256 + h * 32;
    const float* awp  = aw + (size_t)bq * 128 + h * 16;
    const float* vb   = value + ((size_t)b * LEN_V) * 256 + h * 32 + c * 4;

    float4 acc = make_float4(0.f, 0.f, 0.f, 0.f);
    #pragma unroll
    for (int l = 0; l < 4; ++l) {
        const int H = Hs[l], W = Wsz[l], st = Starts[l];
        #pragma unroll
        for (int p = 0; p < 4; ++p) {
            float ox = offp[l * 8 + p * 2 + 0];
            float oy = offp[l * 8 + p * 2 + 1];
            float a_w = awp[l * 4 + p];
            float xx = (rb.x + ox * 0.125f * rb.z) * W - 0.5f;
            float yy = (rb.y + oy * 0.125f * rb.w) * H - 0.5f;
            float x0f = floorf(xx), y0f = floorf(yy);
            float fx = xx - x0f, fy = yy - y0f;
            int x0 = (int)x0f, y0 = (int)y0f;
            #pragma unroll
            for (int dy = 0; dy < 2; ++dy) {
                int yi = y0 + dy;
                float wy = dy ? fy : (1.f - fy);
                bool vy = (yi >= 0) && (yi < H);
                int yc = min(max(yi, 0), H - 1);
                #pragma unroll
                for (int dx = 0; dx < 2; ++dx) {
                    int xi = x0 + dx;
                    float wx = dx ? fx : (1.f - fx);
                    bool vx = (xi >= 0) && (xi < W);
                    int xc = min(max(xi, 0), W - 1);
                    float wgt = a_w * wy * wx * ((vx && vy) ? 1.f : 0.f);
                    float4 g = *(const float4*)(vb + (size_t)(st + yc * W + xc) * 256);
                    acc.x += wgt * g.x; acc.y += wgt * g.y;
                    acc.z += wgt * g.z; acc.w += wgt * g.w;
                }
            }
        }
    }
    *(float4*)(dout + (size_t)bq * 256 + h * 32 + c * 4) = acc;
}

// ---------------------------------------------------------------------------
// LayerNorm(x + dx) * g + b
// ---------------------------------------------------------------------------
__global__ __launch_bounds__(256) void ln_kernel(
    const float* __restrict__ x, const float* __restrict__ dx,
    const float* __restrict__ g, const float* __restrict__ bt,
    float* __restrict__ out, int rows)
{
    int row = blockIdx.x * 4 + (threadIdx.x >> 6);
    if (row >= rows) return;
    int lane = threadIdx.x & 63;
    size_t base = (size_t)row * 256 + lane * 4;
    float4 xv = *(const float4*)(x + base);
    float4 dv = *(const float4*)(dx + base);
    float a0 = xv.x + dv.x, a1 = xv.y + dv.y, a2 = xv.z + dv.z, a3 = xv.w + dv.w;
    float s = a0 + a1 + a2 + a3;
    float s2 = a0 * a0 + a1 * a1 + a2 * a2 + a3 * a3;
    #pragma unroll
    for (int o = 32; o; o >>= 1) {
        s += __shfl_xor(s, o);
        s2 += __shfl_xor(s2, o);
    }
    float mean = s * (1.f / 256.f);
    float var = s2 * (1.f / 256.f) - mean * mean;
    float inv = rsqrtf(var + 1e-5f);
    float4 gv = *(const float4*)(g + lane * 4);
    float4 bv = *(const float4*)(bt + lane * 4);
    float4 r;
    r.x = (a0 - mean) * inv * gv.x + bv.x;
    r.y = (a1 - mean) * inv * gv.y + bv.y;
    r.z = (a2 - mean) * inv * gv.z + bv.z;
    r.w = (a3 - mean) * inv * gv.w + bv.w;
    *(float4*)(out + base) = r;
}

// ---------------------------------------------------------------------------
extern "C" void kernel_launch(void* const* d_in, const int* in_sizes, int n_in,
                              void* d_out, int out_size, void* d_ws, size_t ws_size,
                              hipStream_t stream)
{
    const float* embed = (const float*)d_in[0];
    const float* rbbox = (const float*)d_in[1];
    const float* feats = (const float*)d_in[2];
    const float* qpos  = (const float*)d_in[3];
    const float* Wq = (const float*)d_in[4];  const float* bq = (const float*)d_in[5];
    const float* Wk = (const float*)d_in[6];  const float* bk = (const float*)d_in[7];
    const float* Wv = (const float*)d_in[8];  const float* bv = (const float*)d_in[9];
    const float* Wo = (const float*)d_in[10]; const float* bo = (const float*)d_in[11];
    const float* g1 = (const float*)d_in[12]; const float* b1 = (const float*)d_in[13];
    const float* Wval = (const float*)d_in[14]; const float* bval = (const float*)d_in[15];
    const float* Woff = (const float*)d_in[16]; const float* boff = (const float*)d_in[17];
    const float* Waw  = (const float*)d_in[18]; const float* baw  = (const float*)d_in[19];
    const float* Wop  = (const float*)d_in[20]; const float* bop  = (const float*)d_in[21];
    const float* g2 = (const float*)d_in[22]; const float* b2 = (const float*)d_in[23];
    const float* W1 = (const float*)d_in[24]; const float* bf1 = (const float*)d_in[25];
    const float* W2 = (const float*)d_in[26]; const float* bf2 = (const float*)d_in[27];
    const float* g3 = (const float*)d_in[28]; const float* b3 = (const float*)d_in[29];

    const int M = BS * NQ;                 // 7200
    const int MV = BS * LEN_V;             // 106352
    const size_t E = (size_t)M * DM;       // 1,843,200 floats
    const size_t VAL = (size_t)MV * DM;    // 27,226,112 floats

    float* ws = (float*)d_ws;
    float* valueb = ws;                    // VAL floats
    float* qb   = ws + VAL;                // E
    float* kb   = qb + E;                  // E
    float* vbuf = kb + E;                  // E
    float* attb = vbuf + E;                // E
    float* e1b  = attb + E;                // E
    // attention partials alias the (not-yet-written) value buffer:
    float* partb = valueb;                 // 57600*4*40 = 9.2M floats < VAL
    // aliases (sequentially safe):
    float* sab   = qb;      // Wo output
    float* offb  = kb;      // sampling offsets
    float* awbuf = vbuf;    // attention weights (N=128)
    float* doutb = attb;    // deformable output
    float* cab   = qb;      // Wop output
    float* e2b   = kb;      // embed after LN2
    float* ffhb  = valueb;  // FFN hidden (7200x1024)
    float* ffb   = vbuf;    // FFN output

    dim3 blk(256);
    auto gg = [](int m, int n) { return dim3((m + 63) / 64, n / 64); };

    // 1-3: q, k, v projections
    gemm_kernel<<<gg(M, 256), blk, 0, stream>>>(embed, qpos, Wq, bq, qb, M, 256, 256, 0);
    gemm_kernel<<<gg(M, 256), blk, 0, stream>>>(embed, qpos, Wk, bk, kb, M, 256, 256, 0);
    gemm_kernel<<<gg(M, 256), blk, 0, stream>>>(embed, nullptr, Wv, bv, vbuf, M, 256, 256, 0);
    // 4: self-attention (LDS flash partials + combine)
    {
        dim3 agrid(BS * 8, (NQ + 255) / 256, KSPLIT);  // 64 x 4 x 4
        attn_flash_kernel<<<agrid, blk, 0, stream>>>(qb, kb, vbuf, partb);
        attn_combine_kernel<<<dim3((BS * 8 * NQ + 255) / 256), blk, 0, stream>>>(partb, attb);
    }
    // 5: output projection
    gemm_kernel<<<gg(M, 256), blk, 0, stream>>>(attb, nullptr, Wo, bo, sab, M, 256, 256, 0);
    // 6: LN1
    ln_kernel<<<dim3((M + 3) / 4), blk, 0, stream>>>(embed, sab, g1, b1, e1b, M);
    // 7: value projection (big GEMM) -- overwrites partials (dead now)
    gemm_kernel<<<gg(MV, 256), blk, 0, stream>>>(feats, nullptr, Wval, bval, valueb, MV, 256, 256, 0);
    // 8-9: offsets + attention-weight logits (query = e1 + qpos fused)
    gemm_kernel<<<gg(M, 256), blk, 0, stream>>>(e1b, qpos, Woff, boff, offb, M, 256, 256, 0);
    gemm_kernel<<<gg(M, 128), blk, 0, stream>>>(e1b, qpos, Waw, baw, awbuf, M, 128, 256, 0);
    // 10: softmax over 16
    aw_softmax_kernel<<<dim3((BS * NQ * 8 + 255) / 256), blk, 0, stream>>>(awbuf);
    // 11: deformable sampling
    deform_kernel<<<dim3((BS * NQ * 64 + 255) / 256), blk, 0, stream>>>(valueb, offb, awbuf, rbbox, doutb);
    // 12: output projection of deformable attention
    gemm_kernel<<<gg(M, 256), blk, 0, stream>>>(doutb, nullptr, Wop, bop, cab, M, 256, 256, 0);
    // 13: LN2
    ln_kernel<<<dim3((M + 3) / 4), blk, 0, stream>>>(e1b, cab, g2, b2, e2b, M);
    // 14-15: FFN
    gemm_kernel<<<gg(M, 1024), blk, 0, stream>>>(e2b, nullptr, W1, bf1, ffhb, M, 1024, 256, 1);
    gemm_kernel<<<gg(M, 256), blk, 0, stream>>>(ffhb, nullptr, W2, bf2, ffb, M, 256, 1024, 0);
    // 16: LN3 -> out
    ln_kernel<<<dim3((M + 3) / 4), blk, 0, stream>>>(e2b, ffb, g3, b3, (float*)d_out, M);
}

// Round 4
// 510.279 us; speedup vs baseline: 2.3042x; 1.4516x over previous
//
#include <hip/hip_runtime.h>
#include <hip/hip_bf16.h>
#include <cstddef>

#define BS 8
#define NQ 900
#define DM 256
#define LEN_V 13294
#define KSPLIT 4
#define KCHUNK 225   // 900/4
#define KV_STAGE 64
#define PSTRIDE 40   // floats per partial record: o[32], m@32, l@33, pad->40

using bf16x8 = __attribute__((ext_vector_type(8))) __bf16;
using f32x4  = __attribute__((ext_vector_type(4))) float;

__device__ __forceinline__ unsigned short f2bf(float f) {
    union { float f; unsigned int u; } v; v.f = f;
    unsigned int r = v.u + 0x7FFFu + ((v.u >> 16) & 1u);
    return (unsigned short)(r >> 16);
}

// chunk swizzle: row r, 16B-chunk c stored at position c ^ SW(r); spreads the
// 16-row fragment reads across 8 bank-quads (2-way = free). 
#define SW(r) (((r) + ((r) >> 2)) & 3)

// ---------------------------------------------------------------------------
// Batched weight prep: fp32 W[K][N] -> bf16 WT[N][K], all 10 weights, 1 launch
// ---------------------------------------------------------------------------
struct WDesc { const float* src; unsigned short* dst; int K; int N; };
struct WPrepArgs { WDesc w[10]; };

__global__ __launch_bounds__(256) void wprep_kernel(WPrepArgs args)
{
    WDesc d = args.w[blockIdx.z];
    int k0 = blockIdx.x * 32;
    int n0 = blockIdx.y * 32;
    if (k0 >= d.K || n0 >= d.N) return;
    __shared__ unsigned short t[32][33];
    int tx = threadIdx.x & 31, ty = threadIdx.x >> 5;
    #pragma unroll
    for (int i = 0; i < 4; ++i) {
        int kk = ty + i * 8;
        t[kk][tx] = f2bf(d.src[(size_t)(k0 + kk) * d.N + n0 + tx]);
    }
    __syncthreads();
    #pragma unroll
    for (int i = 0; i < 4; ++i) {
        int nn = ty + i * 8;
        d.dst[(size_t)(n0 + nn) * d.K + k0 + tx] = t[tx][nn];
    }
}

// ---------------------------------------------------------------------------
// bf16 MFMA GEMM: C[M,N] = bf16(A [+A2]) @ B + bias, optional relu.
// A fp32 [M][K] (converted to bf16 during staging), BT bf16 [N][K].
// BM=128, BN=64, BK=32; 256 threads = 4 waves (2x2), wave tile 64x32,
// per wave 4x2 tiles of 16x16, mfma_f32_16x16x32_bf16.
// ---------------------------------------------------------------------------
__global__ __launch_bounds__(256) void gemm_bf16_kernel(
    const float* __restrict__ A, const float* __restrict__ A2,
    const unsigned short* __restrict__ BT, const float* __restrict__ bias,
    float* __restrict__ C, int M, int N, int K, int relu)
{
    __shared__ uint4 As4[128 * 4];   // 8 KB: [row][chunkpos], chunk = 8 bf16
    __shared__ uint4 Bs4[64 * 4];    // 4 KB

    const int tid = threadIdx.x;
    const int lane = tid & 63;
    const int wave = tid >> 6;
    const int wm = wave >> 1;        // 0..1
    const int wn = wave & 1;         // 0..1
    const int row0 = blockIdx.x * 128;
    const int col0 = blockIdx.y * 64;

    f32x4 acc[4][2];
    #pragma unroll
    for (int i = 0; i < 4; ++i)
        #pragma unroll
        for (int j = 0; j < 2; ++j)
            acc[i][j] = {0.f, 0.f, 0.f, 0.f};

    const int ar  = tid >> 1;          // A stage row 0..127
    const int ah  = (tid & 1) * 16;    // float col offset
    const int acb = (tid & 1) * 2;     // chunk base
    const int agr = row0 + ar;
    const bool aok = agr < M;
    const int br  = tid >> 2;          // B stage row 0..63
    const int bseg = tid & 3;          // chunk
    const int bgr = col0 + br;

    const int lr = lane & 15;
    const int lc = lane >> 4;

    const bf16x8* Asb = (const bf16x8*)As4;
    const bf16x8* Bsb = (const bf16x8*)Bs4;

    for (int k0 = 0; k0 < K; k0 += 32) {
        // ---- global loads (fp32 A [+A2], bf16 BT) ----
        float fl[16];
        #pragma unroll
        for (int j = 0; j < 16; ++j) fl[j] = 0.f;
        if (aok) {
            const float* ap = A + (size_t)agr * K + k0 + ah;
            #pragma unroll
            for (int j = 0; j < 4; ++j) {
                float4 t = *(const float4*)(ap + j * 4);
                fl[j*4+0] = t.x; fl[j*4+1] = t.y; fl[j*4+2] = t.z; fl[j*4+3] = t.w;
            }
            if (A2) {
                const float* ap2 = A2 + (size_t)agr * K + k0 + ah;
                #pragma unroll
                for (int j = 0; j < 4; ++j) {
                    float4 t = *(const float4*)(ap2 + j * 4);
                    fl[j*4+0] += t.x; fl[j*4+1] += t.y; fl[j*4+2] += t.z; fl[j*4+3] += t.w;
                }
            }
        }
        uint4 bvq = *(const uint4*)(BT + (size_t)bgr * K + k0 + bseg * 8);

        __syncthreads();   // previous iteration's frag reads complete
        union { unsigned short us[8]; uint4 q; } pk0, pk1;
        #pragma unroll
        for (int j = 0; j < 8; ++j) { pk0.us[j] = f2bf(fl[j]); pk1.us[j] = f2bf(fl[8 + j]); }
        As4[ar * 4 + ((acb + 0) ^ SW(ar))] = pk0.q;
        As4[ar * 4 + ((acb + 1) ^ SW(ar))] = pk1.q;
        Bs4[br * 4 + (bseg ^ SW(br))] = bvq;
        __syncthreads();

        // ---- fragments + MFMA ----
        bf16x8 af[4], bfr[2];
        #pragma unroll
        for (int mi = 0; mi < 4; ++mi) {
            int r = wm * 64 + mi * 16 + lr;
            af[mi] = Asb[r * 4 + (lc ^ SW(r))];
        }
        #pragma unroll
        for (int ni = 0; ni < 2; ++ni) {
            int r = wn * 32 + ni * 16 + lr;
            bfr[ni] = Bsb[r * 4 + (lc ^ SW(r))];
        }
        #pragma unroll
        for (int mi = 0; mi < 4; ++mi)
            #pragma unroll
            for (int ni = 0; ni < 2; ++ni)
                acc[mi][ni] = __builtin_amdgcn_mfma_f32_16x16x32_bf16(
                    af[mi], bfr[ni], acc[mi][ni], 0, 0, 0);
    }

    // ---- epilogue: C/D layout col=lane&15, row=(lane>>4)*4+reg (m89) ----
    #pragma unroll
    for (int ni = 0; ni < 2; ++ni) {
        int col = col0 + wn * 32 + ni * 16 + lr;
        float bval = bias[col];
        #pragma unroll
        for (int mi = 0; mi < 4; ++mi) {
            #pragma unroll
            for (int rg = 0; rg < 4; ++rg) {
                int row = row0 + wm * 64 + mi * 16 + lc * 4 + rg;
                if (row < M) {
                    float o = acc[mi][ni][rg] + bval;
                    if (relu) o = fmaxf(o, 0.f);
                    C[(size_t)row * N + col] = o;
                }
            }
        }
    }
}

// ---------------------------------------------------------------------------
// Flash-style self-attention partial with LDS-staged K/V (unchanged)
// ---------------------------------------------------------------------------
__global__ __launch_bounds__(256) void attn_flash_kernel(
    const float* __restrict__ q, const float* __restrict__ k,
    const float* __restrict__ v, float* __restrict__ part)
{
    const int bh = blockIdx.x;
    const int h = bh & 7, b = bh >> 3;
    const int qi = blockIdx.y * 256 + threadIdx.x;
    const int ks = blockIdx.z;
    const bool active = qi < NQ;
    const int qic = active ? qi : NQ - 1;

    __shared__ float ksh[KV_STAGE][32];
    __shared__ float vsh[KV_STAGE][32];

    const float scale = 0.17677669529663687f;
    float qv[32];
    {
        const float* qp = q + ((size_t)(b * NQ + qic) * DM + h * 32);
        #pragma unroll
        for (int i = 0; i < 8; ++i) {
            float4 f = *(const float4*)(qp + i * 4);
            qv[4 * i + 0] = f.x * scale; qv[4 * i + 1] = f.y * scale;
            qv[4 * i + 2] = f.z * scale; qv[4 * i + 3] = f.w * scale;
        }
    }

    float m = -3.0e38f, l = 0.f;
    float oacc[32];
    #pragma unroll
    for (int d = 0; d < 32; ++d) oacc[d] = 0.f;

    const int j0 = ks * KCHUNK;
    const int j1 = min(NQ, j0 + KCHUNK);
    const int srow = threadIdx.x >> 2;
    const int scol = (threadIdx.x & 3) * 8;

    for (int jb = j0; jb < j1; jb += KV_STAGE) {
        const int cnt = min(KV_STAGE, j1 - jb);
        __syncthreads();
        if (srow < cnt) {
            const float* kp = k + ((size_t)(b * NQ + jb + srow) * DM + h * 32 + scol);
            const float* vp = v + ((size_t)(b * NQ + jb + srow) * DM + h * 32 + scol);
            *(float4*)&ksh[srow][scol]     = *(const float4*)kp;
            *(float4*)&ksh[srow][scol + 4] = *(const float4*)(kp + 4);
            *(float4*)&vsh[srow][scol]     = *(const float4*)vp;
            *(float4*)&vsh[srow][scol + 4] = *(const float4*)(vp + 4);
        }
        __syncthreads();

        const int full = cnt & ~7;
        for (int jj = 0; jj < full; jj += 8) {
            float s[8];
            #pragma unroll
            for (int u = 0; u < 8; ++u) {
                float acc = 0.f;
                #pragma unroll
                for (int i = 0; i < 8; ++i) {
                    float4 f = *(const float4*)&ksh[jj + u][i * 4];
                    acc += qv[4 * i + 0] * f.x + qv[4 * i + 1] * f.y
                         + qv[4 * i + 2] * f.z + qv[4 * i + 3] * f.w;
                }
                s[u] = acc;
            }
            float mc = s[0];
            #pragma unroll
            for (int u = 1; u < 8; ++u) mc = fmaxf(mc, s[u]);
            if (mc > m) {
                float corr = __expf(m - mc);
                l *= corr;
                #pragma unroll
                for (int d = 0; d < 32; ++d) oacc[d] *= corr;
                m = mc;
            }
            #pragma unroll
            for (int u = 0; u < 8; ++u) {
                float p = __expf(s[u] - m);
                l += p;
                #pragma unroll
                for (int i = 0; i < 8; ++i) {
                    float4 f = *(const float4*)&vsh[jj + u][i * 4];
                    oacc[4 * i + 0] += p * f.x; oacc[4 * i + 1] += p * f.y;
                    oacc[4 * i + 2] += p * f.z; oacc[4 * i + 3] += p * f.w;
                }
            }
        }
        for (int jj = full; jj < cnt; ++jj) {
            float sv = 0.f;
            #pragma unroll
            for (int i = 0; i < 8; ++i) {
                float4 f = *(const float4*)&ksh[jj][i * 4];
                sv += qv[4 * i + 0] * f.x + qv[4 * i + 1] * f.y
                    + qv[4 * i + 2] * f.z + qv[4 * i + 3] * f.w;
            }
            if (sv > m) {
                float corr = __expf(m - sv);
                l *= corr;
                #pragma unroll
                for (int d = 0; d < 32; ++d) oacc[d] *= corr;
                m = sv;
            }
            float p = __expf(sv - m);
            l += p;
            #pragma unroll
            for (int i = 0; i < 8; ++i) {
                float4 f = *(const float4*)&vsh[jj][i * 4];
                oacc[4 * i + 0] += p * f.x; oacc[4 * i + 1] += p * f.y;
                oacc[4 * i + 2] += p * f.z; oacc[4 * i + 3] += p * f.w;
            }
        }
    }

    if (active) {
        float* pp = part + ((size_t)(bh * NQ + qi) * KSPLIT + ks) * PSTRIDE;
        #pragma unroll
        for (int i = 0; i < 8; ++i) {
            float4 f;
            f.x = oacc[4 * i + 0]; f.y = oacc[4 * i + 1];
            f.z = oacc[4 * i + 2]; f.w = oacc[4 * i + 3];
            *(float4*)(pp + i * 4) = f;
        }
        pp[32] = m;
        pp[33] = l;
    }
}

// ---------------------------------------------------------------------------
__global__ __launch_bounds__(256) void attn_combine_kernel(
    const float* __restrict__ part, float* __restrict__ out)
{
    int t = blockIdx.x * 256 + threadIdx.x;
    if (t >= BS * 8 * NQ) return;
    int qi = t % NQ;
    int bh = t / NQ;
    int h = bh & 7, b = bh >> 3;

    const float* base = part + (size_t)t * KSPLIT * PSTRIDE;
    float M = -3.0e38f;
    #pragma unroll
    for (int ks = 0; ks < KSPLIT; ++ks)
        M = fmaxf(M, base[ks * PSTRIDE + 32]);
    float L = 0.f;
    float O[32];
    #pragma unroll
    for (int d = 0; d < 32; ++d) O[d] = 0.f;
    #pragma unroll
    for (int ks = 0; ks < KSPLIT; ++ks) {
        const float* pp = base + ks * PSTRIDE;
        float c = __expf(pp[32] - M);
        L += pp[33] * c;
        #pragma unroll
        for (int i = 0; i < 8; ++i) {
            float4 f = *(const float4*)(pp + i * 4);
            O[4 * i + 0] += f.x * c; O[4 * i + 1] += f.y * c;
            O[4 * i + 2] += f.z * c; O[4 * i + 3] += f.w * c;
        }
    }
    float inv = 1.f / L;
    float* op = out + ((size_t)(b * NQ + qi) * DM + h * 32);
    #pragma unroll
    for (int i = 0; i < 8; ++i) {
        float4 f;
        f.x = O[4 * i + 0] * inv; f.y = O[4 * i + 1] * inv;
        f.z = O[4 * i + 2] * inv; f.w = O[4 * i + 3] * inv;
        *(float4*)(op + i * 4) = f;
    }
}

// ---------------------------------------------------------------------------
__global__ __launch_bounds__(256) void aw_softmax_kernel(float* __restrict__ aw)
{
    int t = blockIdx.x * 256 + threadIdx.x;
    if (t >= BS * NQ * 8) return;
    float* p = aw + (size_t)t * 16;
    float vals[16];
    #pragma unroll
    for (int i = 0; i < 4; ++i) {
        float4 f = *(const float4*)(p + i * 4);
        vals[4 * i + 0] = f.x; vals[4 * i + 1] = f.y;
        vals[4 * i + 2] = f.z; vals[4 * i + 3] = f.w;
    }
    float mx = vals[0];
    #pragma unroll
    for (int i = 1; i < 16; ++i) mx = fmaxf(mx, vals[i]);
    float sum = 0.f;
    #pragma unroll
    for (int i = 0; i < 16; ++i) { vals[i] = __expf(vals[i] - mx); sum += vals[i]; }
    float inv = 1.f / sum;
    #pragma unroll
    for (int i = 0; i < 4; ++i) {
        float4 f;
        f.x = vals[4 * i + 0] * inv; f.y = vals[4 * i + 1] * inv;
        f.z = vals[4 * i + 2] * inv; f.w = vals[4 * i + 3] * inv;
        *(float4*)(p + i * 4) = f;
    }
}

// ---------------------------------------------------------------------------
__global__ __launch_bounds__(256) void deform_kernel(
    const float* __restrict__ value, const float* __restrict__ off,
    const float* __restrict__ aw, const float* __restrict__ rbbox,
    float* __restrict__ dout)
{
    int t = blockIdx.x * 256 + threadIdx.x;
    if (t >= BS * NQ * 64) return;
    int c = t & 7;
    int h = (t >> 3) & 7;
    int bq = t >> 6;
    int b = bq / NQ;

    const int Hs[4]     = {100, 50, 25, 13};
    const int Wsz[4]    = {100, 50, 25, 13};
    const int Starts[4] = {0, 10000, 12500, 13125};

    float4 rb = *(const float4*)(rbbox + (size_t)bq * 4);
    const float* offp = off + (size_t)bq * 256 + h * 32;
    const float* awp  = aw + (size_t)bq * 128 + h * 16;
    const float* vb   = value + ((size_t)b * LEN_V) * 256 + h * 32 + c * 4;

    float4 acc = make_float4(0.f, 0.f, 0.f, 0.f);
    #pragma unroll
    for (int l = 0; l < 4; ++l) {
        const int H = Hs[l], W = Wsz[l], st = Starts[l];
        #pragma unroll
        for (int p = 0; p < 4; ++p) {
            float ox = offp[l * 8 + p * 2 + 0];
            float oy = offp[l * 8 + p * 2 + 1];
            float a_w = awp[l * 4 + p];
            float xx = (rb.x + ox * 0.125f * rb.z) * W - 0.5f;
            float yy = (rb.y + oy * 0.125f * rb.w) * H - 0.5f;
            float x0f = floorf(xx), y0f = floorf(yy);
            float fx = xx - x0f, fy = yy - y0f;
            int x0 = (int)x0f, y0 = (int)y0f;
            #pragma unroll
            for (int dy = 0; dy < 2; ++dy) {
                int yi = y0 + dy;
                float wy = dy ? fy : (1.f - fy);
                bool vy = (yi >= 0) && (yi < H);
                int yc = min(max(yi, 0), H - 1);
                #pragma unroll
                for (int dx = 0; dx < 2; ++dx) {
                    int xi = x0 + dx;
                    float wx = dx ? fx : (1.f - fx);
                    bool vx = (xi >= 0) && (xi < W);
                    int xc = min(max(xi, 0), W - 1);
                    float wgt = a_w * wy * wx * ((vx && vy) ? 1.f : 0.f);
                    float4 g = *(const float4*)(vb + (size_t)(st + yc * W + xc) * 256);
                    acc.x += wgt * g.x; acc.y += wgt * g.y;
                    acc.z += wgt * g.z; acc.w += wgt * g.w;
                }
            }
        }
    }
    *(float4*)(dout + (size_t)bq * 256 + h * 32 + c * 4) = acc;
}

// ---------------------------------------------------------------------------
__global__ __launch_bounds__(256) void ln_kernel(
    const float* __restrict__ x, const float* __restrict__ dx,
    const float* __restrict__ g, const float* __restrict__ bt,
    float* __restrict__ out, int rows)
{
    int row = blockIdx.x * 4 + (threadIdx.x >> 6);
    if (row >= rows) return;
    int lane = threadIdx.x & 63;
    size_t base = (size_t)row * 256 + lane * 4;
    float4 xv = *(const float4*)(x + base);
    float4 dv = *(const float4*)(dx + base);
    float a0 = xv.x + dv.x, a1 = xv.y + dv.y, a2 = xv.z + dv.z, a3 = xv.w + dv.w;
    float s = a0 + a1 + a2 + a3;
    float s2 = a0 * a0 + a1 * a1 + a2 * a2 + a3 * a3;
    #pragma unroll
    for (int o = 32; o; o >>= 1) {
        s += __shfl_xor(s, o);
        s2 += __shfl_xor(s2, o);
    }
    float mean = s * (1.f / 256.f);
    float var = s2 * (1.f / 256.f) - mean * mean;
    float inv = rsqrtf(var + 1e-5f);
    float4 gv = *(const float4*)(g + lane * 4);
    float4 bv = *(const float4*)(bt + lane * 4);
    float4 r;
    r.x = (a0 - mean) * inv * gv.x + bv.x;
    r.y = (a1 - mean) * inv * gv.y + bv.y;
    r.z = (a2 - mean) * inv * gv.z + bv.z;
    r.w = (a3 - mean) * inv * gv.w + bv.w;
    *(float4*)(out + base) = r;
}

// ---------------------------------------------------------------------------
extern "C" void kernel_launch(void* const* d_in, const int* in_sizes, int n_in,
                              void* d_out, int out_size, void* d_ws, size_t ws_size,
                              hipStream_t stream)
{
    const float* embed = (const float*)d_in[0];
    const float* rbbox = (const float*)d_in[1];
    const float* feats = (const float*)d_in[2];
    const float* qpos  = (const float*)d_in[3];
    const float* Wq = (const float*)d_in[4];  const float* bq = (const float*)d_in[5];
    const float* Wk = (const float*)d_in[6];  const float* bk = (const float*)d_in[7];
    const float* Wv = (const float*)d_in[8];  const float* bv = (const float*)d_in[9];
    const float* Wo = (const float*)d_in[10]; const float* bo = (const float*)d_in[11];
    const float* g1 = (const float*)d_in[12]; const float* b1 = (const float*)d_in[13];
    const float* Wval = (const float*)d_in[14]; const float* bval = (const float*)d_in[15];
    const float* Woff = (const float*)d_in[16]; const float* boff = (const float*)d_in[17];
    const float* Waw  = (const float*)d_in[18]; const float* baw  = (const float*)d_in[19];
    const float* Wop  = (const float*)d_in[20]; const float* bop  = (const float*)d_in[21];
    const float* g2 = (const float*)d_in[22]; const float* b2 = (const float*)d_in[23];
    const float* W1 = (const float*)d_in[24]; const float* bf1 = (const float*)d_in[25];
    const float* W2 = (const float*)d_in[26]; const float* bf2 = (const float*)d_in[27];
    const float* g3 = (const float*)d_in[28]; const float* b3 = (const float*)d_in[29];

    const int M = BS * NQ;                 // 7200
    const int MV = BS * LEN_V;             // 106352
    const size_t E = (size_t)M * DM;       // 1,843,200 floats
    const size_t VAL = (size_t)MV * DM;    // 27,226,112 floats

    float* ws = (float*)d_ws;
    float* valueb = ws;                    // VAL floats
    float* qb   = ws + VAL;                // E
    float* kb   = qb + E;                  // E
    float* vbuf = kb + E;                  // E
    float* attb = vbuf + E;                // E
    float* e1b  = attb + E;                // E
    unsigned short* wbase = (unsigned short*)(e1b + E);  // bf16 weights ~2MB
    unsigned short* wq_t   = wbase;
    unsigned short* wk_t   = wbase + 65536;
    unsigned short* wv_t   = wbase + 131072;
    unsigned short* wo_t   = wbase + 196608;
    unsigned short* wval_t = wbase + 262144;
    unsigned short* woff_t = wbase + 327680;
    unsigned short* waw_t  = wbase + 393216;   // 32768
    unsigned short* wop_t  = wbase + 425984;
    unsigned short* w1_t   = wbase + 491520;   // 262144
    unsigned short* w2_t   = wbase + 753664;   // 262144

    float* partb = valueb;  // attn partials alias value buffer (dead until Wval)
    float* sab   = qb;      // Wo output
    float* offb  = kb;      // sampling offsets
    float* awbuf = vbuf;    // attention weights (N=128)
    float* doutb = attb;    // deformable output
    float* cab   = qb;      // Wop output
    float* e2b   = kb;      // embed after LN2
    float* ffhb  = valueb;  // FFN hidden fp32 (7200x1024), after deform
    float* ffb   = vbuf;    // FFN output

    dim3 blk(256);
    auto gg = [](int m, int n) { return dim3((m + 127) / 128, n / 64); };

    // 0: weight prep (one launch, all 10 weights)
    {
        WPrepArgs a;
        a.w[0] = {Wq,   wq_t,   256, 256};
        a.w[1] = {Wk,   wk_t,   256, 256};
        a.w[2] = {Wv,   wv_t,   256, 256};
        a.w[3] = {Wo,   wo_t,   256, 256};
        a.w[4] = {Wval, wval_t, 256, 256};
        a.w[5] = {Woff, woff_t, 256, 256};
        a.w[6] = {Waw,  waw_t,  256, 128};
        a.w[7] = {Wop,  wop_t,  256, 256};
        a.w[8] = {W1,   w1_t,   256, 1024};
        a.w[9] = {W2,   w2_t,   1024, 256};
        wprep_kernel<<<dim3(32, 32, 10), blk, 0, stream>>>(a);
    }

    // 1-3: q, k, v projections
    gemm_bf16_kernel<<<gg(M, 256), blk, 0, stream>>>(embed, qpos, wq_t, bq, qb, M, 256, 256, 0);
    gemm_bf16_kernel<<<gg(M, 256), blk, 0, stream>>>(embed, qpos, wk_t, bk, kb, M, 256, 256, 0);
    gemm_bf16_kernel<<<gg(M, 256), blk, 0, stream>>>(embed, nullptr, wv_t, bv, vbuf, M, 256, 256, 0);
    // 4: self-attention (LDS flash partials + combine)
    {
        dim3 agrid(BS * 8, (NQ + 255) / 256, KSPLIT);
        attn_flash_kernel<<<agrid, blk, 0, stream>>>(qb, kb, vbuf, partb);
        attn_combine_kernel<<<dim3((BS * 8 * NQ + 255) / 256), blk, 0, stream>>>(partb, attb);
    }
    // 5: output projection
    gemm_bf16_kernel<<<gg(M, 256), blk, 0, stream>>>(attb, nullptr, wo_t, bo, sab, M, 256, 256, 0);
    // 6: LN1
    ln_kernel<<<dim3((M + 3) / 4), blk, 0, stream>>>(embed, sab, g1, b1, e1b, M);
    // 7: value projection (big GEMM) -- overwrites partials (dead now)
    gemm_bf16_kernel<<<gg(MV, 256), blk, 0, stream>>>(feats, nullptr, wval_t, bval, valueb, MV, 256, 256, 0);
    // 8-9: offsets + attention-weight logits (query = e1 + qpos fused)
    gemm_bf16_kernel<<<gg(M, 256), blk, 0, stream>>>(e1b, qpos, woff_t, boff, offb, M, 256, 256, 0);
    gemm_bf16_kernel<<<gg(M, 128), blk, 0, stream>>>(e1b, qpos, waw_t, baw, awbuf, M, 128, 256, 0);
    // 10: softmax over 16
    aw_softmax_kernel<<<dim3((BS * NQ * 8 + 255) / 256), blk, 0, stream>>>(awbuf);
    // 11: deformable sampling
    deform_kernel<<<dim3((BS * NQ * 64 + 255) / 256), blk, 0, stream>>>(valueb, offb, awbuf, rbbox, doutb);
    // 12: output projection of deformable attention
    gemm_bf16_kernel<<<gg(M, 256), blk, 0, stream>>>(doutb, nullptr, wop_t, bop, cab, M, 256, 256, 0);
    // 13: LN2
    ln_kernel<<<dim3((M + 3) / 4), blk, 0, stream>>>(e1b, cab, g2, b2, e2b, M);
    // 14-15: FFN (relu fused in FFN1)
    gemm_bf16_kernel<<<gg(M, 1024), blk, 0, stream>>>(e2b, nullptr, w1_t, bf1, ffhb, M, 1024, 256, 1);
    gemm_bf16_kernel<<<gg(M, 256), blk, 0, stream>>>(ffhb, nullptr, w2_t, bf2, ffb, M, 256, 1024, 0);
    // 16: LN3 -> out
    ln_kernel<<<dim3((M + 3) / 4), blk, 0, stream>>>(e2b, ffb, g3, b3, (float*)d_out, M);
}

// Round 5
// 359.638 us; speedup vs baseline: 3.2693x; 1.4189x over previous
//
#include <hip/hip_runtime.h>
#include <hip/hip_bf16.h>
#include <cstddef>

#define BS 8
#define NQ 900
#define DM 256
#define LEN_V 13294

using bf16x8 = __attribute__((ext_vector_type(8))) __bf16;
using f32x4  = __attribute__((ext_vector_type(4))) float;

__device__ __forceinline__ unsigned short f2bf(float f) {
    union { float f; unsigned int u; } v; v.f = f;
    unsigned int r = v.u + 0x7FFFu + ((v.u >> 16) & 1u);
    return (unsigned short)(r >> 16);
}

// chunk swizzle for GEMM LDS tiles
#define SW(r) (((r) + ((r) >> 2)) & 3)

// ---------------------------------------------------------------------------
// Batched weight prep: fp32 W[K][N] -> bf16 WT[N][K], all 10 weights, 1 launch
// ---------------------------------------------------------------------------
struct WDesc { const float* src; unsigned short* dst; int K; int N; };
struct WPrepArgs { WDesc w[10]; };

__global__ __launch_bounds__(256) void wprep_kernel(WPrepArgs args)
{
    WDesc d = args.w[blockIdx.z];
    int k0 = blockIdx.x * 32;
    int n0 = blockIdx.y * 32;
    if (k0 >= d.K || n0 >= d.N) return;
    __shared__ unsigned short t[32][33];
    int tx = threadIdx.x & 31, ty = threadIdx.x >> 5;
    #pragma unroll
    for (int i = 0; i < 4; ++i) {
        int kk = ty + i * 8;
        t[kk][tx] = f2bf(d.src[(size_t)(k0 + kk) * d.N + n0 + tx]);
    }
    __syncthreads();
    #pragma unroll
    for (int i = 0; i < 4; ++i) {
        int nn = ty + i * 8;
        d.dst[(size_t)(n0 + nn) * d.K + k0 + tx] = t[tx][nn];
    }
}

// ---------------------------------------------------------------------------
// bf16 MFMA GEMM: C[M,N] = bf16(A [+A2]) @ B + bias, optional relu. (unchanged)
// ---------------------------------------------------------------------------
__global__ __launch_bounds__(256) void gemm_bf16_kernel(
    const float* __restrict__ A, const float* __restrict__ A2,
    const unsigned short* __restrict__ BT, const float* __restrict__ bias,
    float* __restrict__ C, int M, int N, int K, int relu)
{
    __shared__ uint4 As4[128 * 4];
    __shared__ uint4 Bs4[64 * 4];

    const int tid = threadIdx.x;
    const int lane = tid & 63;
    const int wave = tid >> 6;
    const int wm = wave >> 1;
    const int wn = wave & 1;
    const int row0 = blockIdx.x * 128;
    const int col0 = blockIdx.y * 64;

    f32x4 acc[4][2];
    #pragma unroll
    for (int i = 0; i < 4; ++i)
        #pragma unroll
        for (int j = 0; j < 2; ++j)
            acc[i][j] = {0.f, 0.f, 0.f, 0.f};

    const int ar  = tid >> 1;
    const int ah  = (tid & 1) * 16;
    const int acb = (tid & 1) * 2;
    const int agr = row0 + ar;
    const bool aok = agr < M;
    const int br  = tid >> 2;
    const int bseg = tid & 3;
    const int bgr = col0 + br;

    const int lr = lane & 15;
    const int lc = lane >> 4;

    const bf16x8* Asb = (const bf16x8*)As4;
    const bf16x8* Bsb = (const bf16x8*)Bs4;

    for (int k0 = 0; k0 < K; k0 += 32) {
        float fl[16];
        #pragma unroll
        for (int j = 0; j < 16; ++j) fl[j] = 0.f;
        if (aok) {
            const float* ap = A + (size_t)agr * K + k0 + ah;
            #pragma unroll
            for (int j = 0; j < 4; ++j) {
                float4 t = *(const float4*)(ap + j * 4);
                fl[j*4+0] = t.x; fl[j*4+1] = t.y; fl[j*4+2] = t.z; fl[j*4+3] = t.w;
            }
            if (A2) {
                const float* ap2 = A2 + (size_t)agr * K + k0 + ah;
                #pragma unroll
                for (int j = 0; j < 4; ++j) {
                    float4 t = *(const float4*)(ap2 + j * 4);
                    fl[j*4+0] += t.x; fl[j*4+1] += t.y; fl[j*4+2] += t.z; fl[j*4+3] += t.w;
                }
            }
        }
        uint4 bvq = *(const uint4*)(BT + (size_t)bgr * K + k0 + bseg * 8);

        __syncthreads();
        union { unsigned short us[8]; uint4 q; } pk0, pk1;
        #pragma unroll
        for (int j = 0; j < 8; ++j) { pk0.us[j] = f2bf(fl[j]); pk1.us[j] = f2bf(fl[8 + j]); }
        As4[ar * 4 + ((acb + 0) ^ SW(ar))] = pk0.q;
        As4[ar * 4 + ((acb + 1) ^ SW(ar))] = pk1.q;
        Bs4[br * 4 + (bseg ^ SW(br))] = bvq;
        __syncthreads();

        bf16x8 af[4], bfr[2];
        #pragma unroll
        for (int mi = 0; mi < 4; ++mi) {
            int r = wm * 64 + mi * 16 + lr;
            af[mi] = Asb[r * 4 + (lc ^ SW(r))];
        }
        #pragma unroll
        for (int ni = 0; ni < 2; ++ni) {
            int r = wn * 32 + ni * 16 + lr;
            bfr[ni] = Bsb[r * 4 + (lc ^ SW(r))];
        }
        #pragma unroll
        for (int mi = 0; mi < 4; ++mi)
            #pragma unroll
            for (int ni = 0; ni < 2; ++ni)
                acc[mi][ni] = __builtin_amdgcn_mfma_f32_16x16x32_bf16(
                    af[mi], bfr[ni], acc[mi][ni], 0, 0, 0);
    }

    #pragma unroll
    for (int ni = 0; ni < 2; ++ni) {
        int col = col0 + wn * 32 + ni * 16 + lr;
        float bval = bias[col];
        #pragma unroll
        for (int mi = 0; mi < 4; ++mi) {
            #pragma unroll
            for (int rg = 0; rg < 4; ++rg) {
                int row = row0 + wm * 64 + mi * 16 + lc * 4 + rg;
                if (row < M) {
                    float o = acc[mi][ni][rg] + bval;
                    if (relu) o = fmaxf(o, 0.f);
                    C[(size_t)row * N + col] = o;
                }
            }
        }
    }
}

// ---------------------------------------------------------------------------
// MFMA flash self-attention. Grid (64 bh, 15 qtiles), 4 waves/block,
// 16 queries per wave. Per 64-key block: K bf16 [64][32] LDS (swizzled),
// V^T bf16 [32][64] LDS (swizzled). S^T = mfma(K, Q); online softmax with
// per-lane query ownership; P B-frag assembled via shuffles; O^T = mfma(Vt, P).
// ---------------------------------------------------------------------------
__global__ __launch_bounds__(256) void attn_mfma_kernel(
    const float* __restrict__ q, const float* __restrict__ k,
    const float* __restrict__ v, float* __restrict__ out)
{
    __shared__ uint4 Kls[64 * 4];   // 4 KB
    __shared__ uint4 Vtls[32 * 8];  // 4 KB

    const int tid = threadIdx.x;
    const int lane = tid & 63;
    const int wave = tid >> 6;
    const int qcol = lane & 15;
    const int g = lane >> 4;
    const int bh = blockIdx.x;
    const int h = bh & 7, b = bh >> 3;
    const int qg = blockIdx.y * 64 + wave * 16 + qcol;
    const int qc = qg < NQ ? qg : NQ - 1;

    // Q fragment: B-operand, row(N)=q=lane&15, k(dims)=(lane>>4)*8..+7, pre-scaled
    bf16x8 qf;
    {
        const float sc = 0.17677669529663687f; // 1/sqrt(32)
        const float* qp = q + ((size_t)(b * NQ + qc)) * DM + h * 32 + g * 8;
        float4 f0 = *(const float4*)qp;
        float4 f1 = *(const float4*)(qp + 4);
        union { unsigned short us[8]; bf16x8 v8; } pk;
        pk.us[0] = f2bf(f0.x * sc); pk.us[1] = f2bf(f0.y * sc);
        pk.us[2] = f2bf(f0.z * sc); pk.us[3] = f2bf(f0.w * sc);
        pk.us[4] = f2bf(f1.x * sc); pk.us[5] = f2bf(f1.y * sc);
        pk.us[6] = f2bf(f1.z * sc); pk.us[7] = f2bf(f1.w * sc);
        qf = pk.v8;
    }

    float mrun = -3.0e38f, lrun = 0.f;
    f32x4 oacc[2];
    oacc[0] = {0.f, 0.f, 0.f, 0.f};
    oacc[1] = {0.f, 0.f, 0.f, 0.f};
    const f32x4 zacc = {0.f, 0.f, 0.f, 0.f};

    const int kidx = tid >> 2, kdc = tid & 3;  // K staging: key, dim-chunk(8)
    const int vkp = tid >> 3, vdc = tid & 7;   // V staging: key-pair, dim-quad(4)
    const bf16x8* Kb = (const bf16x8*)Kls;
    const bf16x8* Vb = (const bf16x8*)Vtls;
    unsigned int* V32 = (unsigned int*)Vtls;

    for (int jb = 0; jb < NQ; jb += 64) {
        __syncthreads();
        // ---- stage K[64][32] bf16, chunk swizzle (kdc ^ ((key>>1)&3)) ----
        {
            int gk = jb + kidx;
            float4 f0 = make_float4(0.f, 0.f, 0.f, 0.f), f1 = f0;
            if (gk < NQ) {
                const float* kp = k + ((size_t)(b * NQ + gk)) * DM + h * 32 + kdc * 8;
                f0 = *(const float4*)kp;
                f1 = *(const float4*)(kp + 4);
            }
            union { unsigned short us[8]; uint4 u; } pk;
            pk.us[0] = f2bf(f0.x); pk.us[1] = f2bf(f0.y);
            pk.us[2] = f2bf(f0.z); pk.us[3] = f2bf(f0.w);
            pk.us[4] = f2bf(f1.x); pk.us[5] = f2bf(f1.y);
            pk.us[6] = f2bf(f1.z); pk.us[7] = f2bf(f1.w);
            Kls[kidx * 4 + (kdc ^ ((kidx >> 1) & 3))] = pk.u;
        }
        // ---- stage V^T[32][64] bf16, pair-packed, chunk swizzle ((kp>>2)^(d&7)) ----
        {
            int k0g = jb + 2 * vkp;
            float4 v0 = make_float4(0.f, 0.f, 0.f, 0.f), v1 = v0;
            if (k0g < NQ)
                v0 = *(const float4*)(v + ((size_t)(b * NQ + k0g)) * DM + h * 32 + vdc * 4);
            if (k0g + 1 < NQ)
                v1 = *(const float4*)(v + ((size_t)(b * NQ + k0g + 1)) * DM + h * 32 + vdc * 4);
            float a0[4] = {v0.x, v0.y, v0.z, v0.w};
            float a1[4] = {v1.x, v1.y, v1.z, v1.w};
            #pragma unroll
            for (int j = 0; j < 4; ++j) {
                int d = vdc * 4 + j;
                unsigned int val = (unsigned int)f2bf(a0[j]) | ((unsigned int)f2bf(a1[j]) << 16);
                V32[d * 32 + ((vkp >> 2) ^ (d & 7)) * 4 + (vkp & 3)] = val;
            }
        }
        __syncthreads();

        // ---- QK^T: S^T[key][q], 4 tiles of 16 keys ----
        f32x4 sacc[4];
        #pragma unroll
        for (int kt = 0; kt < 4; ++kt) {
            int key = kt * 16 + qcol;
            bf16x8 kf = Kb[key * 4 + (g ^ ((key >> 1) & 3))];
            sacc[kt] = __builtin_amdgcn_mfma_f32_16x16x32_bf16(kf, qf, zacc, 0, 0, 0);
        }
        if (jb + 64 > NQ) {   // mask padded keys (last block only)
            #pragma unroll
            for (int kt = 0; kt < 4; ++kt)
                #pragma unroll
                for (int r = 0; r < 4; ++r)
                    if (jb + kt * 16 + 4 * g + r >= NQ) sacc[kt][r] = -3.0e38f;
        }

        // ---- online softmax: lane owns query q=lane&15; keys spread over g ----
        float mloc = -3.0e38f;
        #pragma unroll
        for (int kt = 0; kt < 4; ++kt)
            #pragma unroll
            for (int r = 0; r < 4; ++r)
                mloc = fmaxf(mloc, sacc[kt][r]);
        mloc = fmaxf(mloc, __shfl_xor(mloc, 16));
        mloc = fmaxf(mloc, __shfl_xor(mloc, 32));
        float mnew = fmaxf(mrun, mloc);
        float corr = __expf(mrun - mnew);
        mrun = mnew;

        float lloc = 0.f;
        unsigned int pk2[4][2];
        #pragma unroll
        for (int kt = 0; kt < 4; ++kt) {
            float p0 = __expf(sacc[kt][0] - mnew);
            float p1 = __expf(sacc[kt][1] - mnew);
            float p2 = __expf(sacc[kt][2] - mnew);
            float p3 = __expf(sacc[kt][3] - mnew);
            lloc += p0 + p1 + p2 + p3;
            pk2[kt][0] = (unsigned int)f2bf(p0) | ((unsigned int)f2bf(p1) << 16);
            pk2[kt][1] = (unsigned int)f2bf(p2) | ((unsigned int)f2bf(p3) << 16);
        }
        lloc += __shfl_xor(lloc, 16);
        lloc += __shfl_xor(lloc, 32);
        lrun = lrun * corr + lloc;
        #pragma unroll
        for (int ni = 0; ni < 2; ++ni)
            #pragma unroll
            for (int r = 0; r < 4; ++r)
                oacc[ni][r] *= corr;

        // ---- P B-frag assembly (in-register transpose) + PV ----
        const int s0 = qcol + 32 * (g & 1);
        const bool hi = (g >> 1) != 0;
        #pragma unroll
        for (int tp = 0; tp < 2; ++tp) {
            int A0 = (int)pk2[2 * tp][0], A1 = (int)pk2[2 * tp][1];
            int B0 = (int)pk2[2 * tp + 1][0], B1 = (int)pk2[2 * tp + 1][1];
            int a0 = __shfl(A0, s0),      a1 = __shfl(A1, s0);
            int b0 = __shfl(B0, s0),      b1 = __shfl(B1, s0);
            int a2 = __shfl(A0, s0 + 16), a3 = __shfl(A1, s0 + 16);
            int b2 = __shfl(B0, s0 + 16), b3 = __shfl(B1, s0 + 16);
            union { unsigned int u[4]; bf16x8 v8; } pf;
            pf.u[0] = hi ? (unsigned int)b0 : (unsigned int)a0;
            pf.u[1] = hi ? (unsigned int)b1 : (unsigned int)a1;
            pf.u[2] = hi ? (unsigned int)b2 : (unsigned int)a2;
            pf.u[3] = hi ? (unsigned int)b3 : (unsigned int)a3;
            #pragma unroll
            for (int ni = 0; ni < 2; ++ni) {
                int d = ni * 16 + qcol;
                bf16x8 vf = Vb[d * 8 + ((4 * tp + g) ^ (d & 7))];
                oacc[ni] = __builtin_amdgcn_mfma_f32_16x16x32_bf16(vf, pf.v8, oacc[ni], 0, 0, 0);
            }
        }
    }

    // ---- epilogue: O^T lane holds d = 16*ni + 4g + r for its query ----
    if (qg < NQ) {
        float inv = 1.f / lrun;
        float* op = out + ((size_t)(b * NQ + qg)) * DM + h * 32;
        float4 o0, o1;
        o0.x = oacc[0][0] * inv; o0.y = oacc[0][1] * inv;
        o0.z = oacc[0][2] * inv; o0.w = oacc[0][3] * inv;
        o1.x = oacc[1][0] * inv; o1.y = oacc[1][1] * inv;
        o1.z = oacc[1][2] * inv; o1.w = oacc[1][3] * inv;
        *(float4*)(op + 4 * g) = o0;
        *(float4*)(op + 16 + 4 * g) = o1;
    }
}

// ---------------------------------------------------------------------------
__global__ __launch_bounds__(256) void aw_softmax_kernel(float* __restrict__ aw)
{
    int t = blockIdx.x * 256 + threadIdx.x;
    if (t >= BS * NQ * 8) return;
    float* p = aw + (size_t)t * 16;
    float vals[16];
    #pragma unroll
    for (int i = 0; i < 4; ++i) {
        float4 f = *(const float4*)(p + i * 4);
        vals[4 * i + 0] = f.x; vals[4 * i + 1] = f.y;
        vals[4 * i + 2] = f.z; vals[4 * i + 3] = f.w;
    }
    float mx = vals[0];
    #pragma unroll
    for (int i = 1; i < 16; ++i) mx = fmaxf(mx, vals[i]);
    float sum = 0.f;
    #pragma unroll
    for (int i = 0; i < 16; ++i) { vals[i] = __expf(vals[i] - mx); sum += vals[i]; }
    float inv = 1.f / sum;
    #pragma unroll
    for (int i = 0; i < 4; ++i) {
        float4 f;
        f.x = vals[4 * i + 0] * inv; f.y = vals[4 * i + 1] * inv;
        f.z = vals[4 * i + 2] * inv; f.w = vals[4 * i + 3] * inv;
        *(float4*)(p + i * 4) = f;
    }
}

// ---------------------------------------------------------------------------
__global__ __launch_bounds__(256) void deform_kernel(
    const float* __restrict__ value, const float* __restrict__ off,
    const float* __restrict__ aw, const float* __restrict__ rbbox,
    float* __restrict__ dout)
{
    int t = blockIdx.x * 256 + threadIdx.x;
    if (t >= BS * NQ * 64) return;
    int c = t & 7;
    int h = (t >> 3) & 7;
    int bq = t >> 6;
    int b = bq / NQ;

    const int Hs[4]     = {100, 50, 25, 13};
    const int Wsz[4]    = {100, 50, 25, 13};
    const int Starts[4] = {0, 10000, 12500, 13125};

    float4 rb = *(const float4*)(rbbox + (size_t)bq * 4);
    const float* offp = off + (size_t)bq * 256 + h * 32;
    const float* awp  = aw + (size_t)bq * 128 + h * 16;
    const float* vb   = value + ((size_t)b * LEN_V) * 256 + h * 32 + c * 4;

    float4 acc = make_float4(0.f, 0.f, 0.f, 0.f);
    #pragma unroll
    for (int l = 0; l < 4; ++l) {
        const int H = Hs[l], W = Wsz[l], st = Starts[l];
        #pragma unroll
        for (int p = 0; p < 4; ++p) {
            float ox = offp[l * 8 + p * 2 + 0];
            float oy = offp[l * 8 + p * 2 + 1];
            float a_w = awp[l * 4 + p];
            float xx = (rb.x + ox * 0.125f * rb.z) * W - 0.5f;
            float yy = (rb.y + oy * 0.125f * rb.w) * H - 0.5f;
            float x0f = floorf(xx), y0f = floorf(yy);
            float fx = xx - x0f, fy = yy - y0f;
            int x0 = (int)x0f, y0 = (int)y0f;
            #pragma unroll
            for (int dy = 0; dy < 2; ++dy) {
                int yi = y0 + dy;
                float wy = dy ? fy : (1.f - fy);
                bool vy = (yi >= 0) && (yi < H);
                int yc = min(max(yi, 0), H - 1);
                #pragma unroll
                for (int dx = 0; dx < 2; ++dx) {
                    int xi = x0 + dx;
                    float wx = dx ? fx : (1.f - fx);
                    bool vx = (xi >= 0) && (xi < W);
                    int xc = min(max(xi, 0), W - 1);
                    float wgt = a_w * wy * wx * ((vx && vy) ? 1.f : 0.f);
                    float4 g = *(const float4*)(vb + (size_t)(st + yc * W + xc) * 256);
                    acc.x += wgt * g.x; acc.y += wgt * g.y;
                    acc.z += wgt * g.z; acc.w += wgt * g.w;
                }
            }
        }
    }
    *(float4*)(dout + (size_t)bq * 256 + h * 32 + c * 4) = acc;
}

// ---------------------------------------------------------------------------
__global__ __launch_bounds__(256) void ln_kernel(
    const float* __restrict__ x, const float* __restrict__ dx,
    const float* __restrict__ g, const float* __restrict__ bt,
    float* __restrict__ out, int rows)
{
    int row = blockIdx.x * 4 + (threadIdx.x >> 6);
    if (row >= rows) return;
    int lane = threadIdx.x & 63;
    size_t base = (size_t)row * 256 + lane * 4;
    float4 xv = *(const float4*)(x + base);
    float4 dv = *(const float4*)(dx + base);
    float a0 = xv.x + dv.x, a1 = xv.y + dv.y, a2 = xv.z + dv.z, a3 = xv.w + dv.w;
    float s = a0 + a1 + a2 + a3;
    float s2 = a0 * a0 + a1 * a1 + a2 * a2 + a3 * a3;
    #pragma unroll
    for (int o = 32; o; o >>= 1) {
        s += __shfl_xor(s, o);
        s2 += __shfl_xor(s2, o);
    }
    float mean = s * (1.f / 256.f);
    float var = s2 * (1.f / 256.f) - mean * mean;
    float inv = rsqrtf(var + 1e-5f);
    float4 gv = *(const float4*)(g + lane * 4);
    float4 bv = *(const float4*)(bt + lane * 4);
    float4 r;
    r.x = (a0 - mean) * inv * gv.x + bv.x;
    r.y = (a1 - mean) * inv * gv.y + bv.y;
    r.z = (a2 - mean) * inv * gv.z + bv.z;
    r.w = (a3 - mean) * inv * gv.w + bv.w;
    *(float4*)(out + base) = r;
}

// ---------------------------------------------------------------------------
extern "C" void kernel_launch(void* const* d_in, const int* in_sizes, int n_in,
                              void* d_out, int out_size, void* d_ws, size_t ws_size,
                              hipStream_t stream)
{
    const float* embed = (const float*)d_in[0];
    const float* rbbox = (const float*)d_in[1];
    const float* feats = (const float*)d_in[2];
    const float* qpos  = (const float*)d_in[3];
    const float* Wq = (const float*)d_in[4];  const float* bq = (const float*)d_in[5];
    const float* Wk = (const float*)d_in[6];  const float* bk = (const float*)d_in[7];
    const float* Wv = (const float*)d_in[8];  const float* bv = (const float*)d_in[9];
    const float* Wo = (const float*)d_in[10]; const float* bo = (const float*)d_in[11];
    const float* g1 = (const float*)d_in[12]; const float* b1 = (const float*)d_in[13];
    const float* Wval = (const float*)d_in[14]; const float* bval = (const float*)d_in[15];
    const float* Woff = (const float*)d_in[16]; const float* boff = (const float*)d_in[17];
    const float* Waw  = (const float*)d_in[18]; const float* baw  = (const float*)d_in[19];
    const float* Wop  = (const float*)d_in[20]; const float* bop  = (const float*)d_in[21];
    const float* g2 = (const float*)d_in[22]; const float* b2 = (const float*)d_in[23];
    const float* W1 = (const float*)d_in[24]; const float* bf1 = (const float*)d_in[25];
    const float* W2 = (const float*)d_in[26]; const float* bf2 = (const float*)d_in[27];
    const float* g3 = (const float*)d_in[28]; const float* b3 = (const float*)d_in[29];

    const int M = BS * NQ;                 // 7200
    const int MV = BS * LEN_V;             // 106352
    const size_t E = (size_t)M * DM;       // 1,843,200 floats
    const size_t VAL = (size_t)MV * DM;    // 27,226,112 floats

    float* ws = (float*)d_ws;
    float* valueb = ws;                    // VAL floats
    float* qb   = ws + VAL;                // E
    float* kb   = qb + E;                  // E
    float* vbuf = kb + E;                  // E
    float* attb = vbuf + E;                // E
    float* e1b  = attb + E;                // E
    unsigned short* wbase = (unsigned short*)(e1b + E);  // bf16 weights ~2MB
    unsigned short* wq_t   = wbase;
    unsigned short* wk_t   = wbase + 65536;
    unsigned short* wv_t   = wbase + 131072;
    unsigned short* wo_t   = wbase + 196608;
    unsigned short* wval_t = wbase + 262144;
    unsigned short* woff_t = wbase + 327680;
    unsigned short* waw_t  = wbase + 393216;
    unsigned short* wop_t  = wbase + 425984;
    unsigned short* w1_t   = wbase + 491520;
    unsigned short* w2_t   = wbase + 753664;

    float* sab   = qb;      // Wo output
    float* offb  = kb;      // sampling offsets
    float* awbuf = vbuf;    // attention weights (N=128)
    float* doutb = attb;    // deformable output
    float* cab   = qb;      // Wop output
    float* e2b   = kb;      // embed after LN2
    float* ffhb  = valueb;  // FFN hidden fp32 (7200x1024), after deform
    float* ffb   = vbuf;    // FFN output

    dim3 blk(256);
    auto gg = [](int m, int n) { return dim3((m + 127) / 128, n / 64); };

    // 0: weight prep
    {
        WPrepArgs a;
        a.w[0] = {Wq,   wq_t,   256, 256};
        a.w[1] = {Wk,   wk_t,   256, 256};
        a.w[2] = {Wv,   wv_t,   256, 256};
        a.w[3] = {Wo,   wo_t,   256, 256};
        a.w[4] = {Wval, wval_t, 256, 256};
        a.w[5] = {Woff, woff_t, 256, 256};
        a.w[6] = {Waw,  waw_t,  256, 128};
        a.w[7] = {Wop,  wop_t,  256, 256};
        a.w[8] = {W1,   w1_t,   256, 1024};
        a.w[9] = {W2,   w2_t,   1024, 256};
        wprep_kernel<<<dim3(32, 32, 10), blk, 0, stream>>>(a);
    }

    // 1-3: q, k, v projections
    gemm_bf16_kernel<<<gg(M, 256), blk, 0, stream>>>(embed, qpos, wq_t, bq, qb, M, 256, 256, 0);
    gemm_bf16_kernel<<<gg(M, 256), blk, 0, stream>>>(embed, qpos, wk_t, bk, kb, M, 256, 256, 0);
    gemm_bf16_kernel<<<gg(M, 256), blk, 0, stream>>>(embed, nullptr, wv_t, bv, vbuf, M, 256, 256, 0);
    // 4: self-attention (MFMA flash, full key sweep, no combine)
    attn_mfma_kernel<<<dim3(BS * 8, (NQ + 63) / 64), blk, 0, stream>>>(qb, kb, vbuf, attb);
    // 5: output projection
    gemm_bf16_kernel<<<gg(M, 256), blk, 0, stream>>>(attb, nullptr, wo_t, bo, sab, M, 256, 256, 0);
    // 6: LN1
    ln_kernel<<<dim3((M + 3) / 4), blk, 0, stream>>>(embed, sab, g1, b1, e1b, M);
    // 7: value projection (big GEMM)
    gemm_bf16_kernel<<<gg(MV, 256), blk, 0, stream>>>(feats, nullptr, wval_t, bval, valueb, MV, 256, 256, 0);
    // 8-9: offsets + attention-weight logits (query = e1 + qpos fused)
    gemm_bf16_kernel<<<gg(M, 256), blk, 0, stream>>>(e1b, qpos, woff_t, boff, offb, M, 256, 256, 0);
    gemm_bf16_kernel<<<gg(M, 128), blk, 0, stream>>>(e1b, qpos, waw_t, baw, awbuf, M, 128, 256, 0);
    // 10: softmax over 16
    aw_softmax_kernel<<<dim3((BS * NQ * 8 + 255) / 256), blk, 0, stream>>>(awbuf);
    // 11: deformable sampling
    deform_kernel<<<dim3((BS * NQ * 64 + 255) / 256), blk, 0, stream>>>(valueb, offb, awbuf, rbbox, doutb);
    // 12: output projection of deformable attention
    gemm_bf16_kernel<<<gg(M, 256), blk, 0, stream>>>(doutb, nullptr, wop_t, bop, cab, M, 256, 256, 0);
    // 13: LN2
    ln_kernel<<<dim3((M + 3) / 4), blk, 0, stream>>>(e1b, cab, g2, b2, e2b, M);
    // 14-15: FFN (relu fused in FFN1)
    gemm_bf16_kernel<<<gg(M, 1024), blk, 0, stream>>>(e2b, nullptr, w1_t, bf1, ffhb, M, 1024, 256, 1);
    gemm_bf16_kernel<<<gg(M, 256), blk, 0, stream>>>(ffhb, nullptr, w2_t, bf2, ffb, M, 256, 1024, 0);
    // 16: LN3 -> out
    ln_kernel<<<dim3((M + 3) / 4), blk, 0, stream>>>(e2b, ffb, g3, b3, (float*)d_out, M);
}